// Round 10
// baseline (1640.496 us; speedup 1.0000x reference)
//
#include <hip/hip_runtime.h>
#include <math.h>

// MultiScaleCodebook on MI355X — round 24: coalesce the stragglers.
// r23 = 1597us (best). argmin at ~75% of 6-MFMA wall, issue ~90% — local
// optimum (r19/r22 restructures both regressed). This round: (1) zcl
// transpose moved out of prep into an LDS-tile kernel (z was read at 4KB
// lane stride = 64 lines/wave-load); (2) embst -> LDS-tile transpose (accu
// was read at 512B lane stride); (3) refine grid (1024,8)->(256,8) with
// stride-256 flag loop (8192 mostly-empty block dispatches -> 2048).
// All bit-identical. Everything else = r23.

#define NCODES 16384
#define NELEM  524288   // 8*64*4*16*16
#define NSP    8192     // 8*4*16*16

#define RCH    8        // refine chunks
#define RCODES (NCODES / RCH)   // 2048 codes per chunk
#define RGRID  256      // refine grid.x (flag stride)

#define WS_ACCU   0ul
#define WS_HUP    4194304ul    // hup f32, 2MB used of 4MB
#define WS_REST64 8388608ul    // rest64 f64 4MB [8388608,12582912)
#define WS_PACC   8388608ul    // pacc f32[2][NELEM] 4MB aliases rest64
#define WS_PART   12582912ul   // <=2MB used; ppool + refine pbest alias this
#define WS_ZCL    16777216ul
#define WS_EHF    18874368ul   // emb bf16-hi frags, 2MB
#define WS_ELF    20971520ul   // emb bf16-lo frags, 2MB
#define WS_ESQ    23068672ul
#define WS_TWT    23134208ul
#define WS_IDX    24903680ul
#define WS_CNT    24936448ul
#define WS_FLAGL  25001984ul
#define WS_FLAGC  25034752ul
#define WS_SSE    25034816ul
#define WS_ENT    25034824ul
#define WS_USED   25034832ul
#define WS_RHF    25034848ul   // rest bf16-hi frags, 1MB
#define WS_RLF    26083424ul   // rest bf16-lo frags, 1MB

typedef __attribute__((ext_vector_type(8))) short short8;
typedef __attribute__((ext_vector_type(4))) float floatx4;

struct PBest { double d; int idx; int pad; };

// async 16B global->LDS: lds dest = wave-uniform base + lane*16
__device__ __forceinline__ void gl2lds16(const void* g, void* l) {
  __builtin_amdgcn_global_load_lds(
      (const __attribute__((address_space(1))) unsigned int*)g,
      (__attribute__((address_space(3))) unsigned int*)l, 16, 0, 0);
}

// round-to-nearest-even float -> bf16; also returns hi as float
__device__ inline short bf16rne(float f, float* hi) {
  unsigned u = __float_as_uint(f);
  unsigned r = (u + 0x7FFFu + ((u >> 16) & 1u)) >> 16;
  *hi = __uint_as_float(r << 16);
  return (short)r;
}

// ---------------------------------------------------------------- prep
// (zcl transpose moved to zclT_kernel; grid = 8001 blocks)
__global__ __launch_bounds__(256) void prep_kernel(
    const float* __restrict__ z, const float* __restrict__ emb, const float* __restrict__ Wq,
    double* __restrict__ accu,
    short* __restrict__ ehf, short* __restrict__ elf,
    float* __restrict__ esq, float* __restrict__ twt,
    int* __restrict__ counts, int* __restrict__ flagcnt,
    double* sse, double* ent, int* usedcnt)
{
  int i = blockIdx.x * 256 + threadIdx.x;
  if (i < NELEM) { accu[i] = 0.0; return; }
  i -= NELEM;
  if (i < NCODES * 64) {  // emb -> bf16 split, MFMA B-frag order
    int j = i >> 6, c = i & 63;
    float v = emb[i];
    float hi; short h = bf16rne(v, &hi);
    float hi2; short l = bf16rne(v - hi, &hi2);
    int jt = j >> 4, nn = j & 15, hf = c >> 5, q = (c >> 3) & 3, ii = c & 7;
    size_t slot = ((size_t)(((jt * 2 + hf) * 64) + q * 16 + nn)) * 8 + ii;
    ehf[slot] = h; elf[slot] = l;
    return;
  }
  i -= NCODES * 64;
  if (i < NCODES) {  // e_sq fp32 (ranking only; refine is fp64)
    float s = 0.f;
    for (int c = 0; c < 64; c++) { float v = emb[i * 64 + c]; s += v * v; }
    esq[i] = s; return;
  }
  i -= NCODES;
  if (i < 442368) {  // twt[qi][tap][ci][co] = Wq[qi][co][ci][tap]
    int qi = i / 110592; int r = i % 110592;
    int tap = r >> 12; int ci = (r >> 6) & 63; int co = r & 63;
    twt[i] = Wq[((qi * 64 + co) * 64 + ci) * 27 + tap];
    return;
  }
  i -= 442368;
  if (i < NCODES) { counts[i] = 0; return; }
  i -= NCODES;
  if (i < 16) {
    if (i < 10) flagcnt[i] = 0;
    else if (i == 10) *sse = 0.0;
    else if (i == 11) *ent = 0.0;
    else if (i == 12) *usedcnt = 0;
  }
}

// ---------------- z [B,C,T,H,W] -> zcl [B,T,H,W,C], LDS-tile transpose
// grid 512 = [b:3][t:2][h:4]; tile 64c x 16w per block.
__global__ __launch_bounds__(256) void zclT_kernel(
    const float* __restrict__ z, float* __restrict__ zcl)
{
  __shared__ float tile[64][17];
  int bid = blockIdx.x;
  int h = bid & 15, t = (bid >> 4) & 3, b = bid >> 6;
  int tid = threadIdx.x;
#pragma unroll
  for (int k = 0; k < 4; k++) {  // read: lane varies w (16) then c -> 4x64B segs
    int elem = tid + k * 256;
    int c = elem >> 4, w = elem & 15;
    tile[c][w] = z[(((b * 64 + c) * 4 + t) * 16 + h) * 16 + w];
  }
  __syncthreads();
#pragma unroll
  for (int k = 0; k < 4; k++) {  // write: lane varies c -> 256B contiguous
    int elem = tid + k * 256;
    int w = elem >> 6, c = elem & 63;
    zcl[(size_t)((((b * 4 + t) * 16 + h) * 16 + w) * 64 + c)] = tile[c][w];
  }
}

// ------------------------------------------- pool (area) + frag emit
// single-stage path (SPLIT==1 scales: N >= ~1k, tiny M per n)
__global__ __launch_bounds__(256) void pool_kernel(
    const float* __restrict__ zcl, const double* __restrict__ accu,
    double* __restrict__ rest64, short* __restrict__ rhf, short* __restrict__ rlf,
    int N, int tpn, int pn)
{
  __shared__ double psum[4][64];
  int n = blockIdx.x;
  int tid = threadIdx.x;
  int c = tid & 63, ck = tid >> 6;
  if (n >= N) {  // zero pad rows so argmin frags are defined
    if (tid < 64) {
      int pt = n >> 4, m = n & 15, hf = tid >> 5, q = (tid >> 3) & 3, ii = tid & 7;
      size_t slot = ((size_t)(((pt * 2 + hf) * 64) + q * 16 + m)) * 8 + ii;
      rhf[slot] = 0; rlf[slot] = 0;
    }
    return;
  }
  int ppn = pn * pn;
  int b = n / (tpn * ppn); int r = n % (tpn * ppn);
  int u = r / ppn; r %= ppn; int v = r / pn; int x = r % pn;
  int t0 = (u * 4) / tpn, t1 = ((u + 1) * 4 + tpn - 1) / tpn;
  int h0 = (v * 16) / pn, h1 = ((v + 1) * 16 + pn - 1) / pn;
  int w0 = (x * 16) / pn, w1 = ((x + 1) * 16 + pn - 1) / pn;
  int nt = t1 - t0, nh = h1 - h0, nw = w1 - w0;
  int M = nt * nh * nw;
  int chunk = (M + 3) >> 2;
  int m0 = ck * chunk; int m1 = m0 + chunk; if (m1 > M) m1 = M;
  double s = 0.0;
  if (m0 < m1) {
    int tmp = m0 / nw; int wi = m0 - tmp * nw;
    int ti = tmp / nh; int hi = tmp - ti * nh;
    for (int m = m0; m < m1; m++) {
      size_t off = (size_t)((((b * 4 + t0 + ti) * 16 + h0 + hi) * 16 + w0 + wi) * 64 + c);
      s += (double)zcl[off] - accu[off];
      if (++wi == nw) { wi = 0; if (++hi == nh) { hi = 0; ++ti; } }
    }
  }
  psum[ck][c] = s;
  __syncthreads();
  if (tid < 64) {
    double t = ((psum[0][c] + psum[1][c]) + psum[2][c]) + psum[3][c];
    float wt = 1.f / (float)nt, wh = 1.f / (float)nh, ww = 1.f / (float)nw;
    double rv = t * (double)wt * (double)wh * (double)ww;
    rest64[(size_t)n * 64 + c] = rv;
    float rv32 = (float)rv;
    float hi; short h = bf16rne(rv32, &hi);
    float hi2; short l = bf16rne(rv32 - hi, &hi2);
    int pt = n >> 4, m = n & 15, hf = c >> 5, q = (c >> 3) & 3, ii = c & 7;
    size_t slot = ((size_t)(((pt * 2 + hf) * 64) + q * 16 + m)) * 8 + ii;
    rhf[slot] = h; rlf[slot] = l;
  }
}

// ------------------- pool stage 1: split-K partials (small-N scales)
__global__ __launch_bounds__(256) void pool_part_kernel(
    const float* __restrict__ zcl, const double* __restrict__ accu,
    double* __restrict__ ppool, int N, int tpn, int pn, int SPL)
{
  __shared__ double psum[4][64];
  int n = blockIdx.x;
  int sp = blockIdx.y;
  int tid = threadIdx.x;
  int c = tid & 63, ck = tid >> 6;
  int ppn = pn * pn;
  int b = n / (tpn * ppn); int r = n % (tpn * ppn);
  int u = r / ppn; r %= ppn; int v = r / pn; int x = r % pn;
  int t0 = (u * 4) / tpn, t1 = ((u + 1) * 4 + tpn - 1) / tpn;
  int h0 = (v * 16) / pn, h1 = ((v + 1) * 16 + pn - 1) / pn;
  int w0 = (x * 16) / pn, w1 = ((x + 1) * 16 + pn - 1) / pn;
  int nt = t1 - t0, nh = h1 - h0, nw = w1 - w0;
  int M = nt * nh * nw;
  int C = SPL * 4;
  int chunk = (M + C - 1) / C;
  int m0 = (sp * 4 + ck) * chunk; int m1 = m0 + chunk;
  if (m0 > M) m0 = M;
  if (m1 > M) m1 = M;
  double s = 0.0;
  if (m0 < m1) {
    int tmp = m0 / nw; int wi = m0 - tmp * nw;
    int ti = tmp / nh; int hi = tmp - ti * nh;
    for (int m = m0; m < m1; m++) {
      size_t off = (size_t)((((b * 4 + t0 + ti) * 16 + h0 + hi) * 16 + w0 + wi) * 64 + c);
      s += (double)zcl[off] - accu[off];
      if (++wi == nw) { wi = 0; if (++hi == nh) { hi = 0; ++ti; } }
    }
  }
  psum[ck][c] = s;
  __syncthreads();
  if (tid < 64) {
    double t = ((psum[0][c] + psum[1][c]) + psum[2][c]) + psum[3][c];
    ppool[((size_t)n * SPL + sp) * 64 + c] = t;
  }
}

// ------------------- pool stage 2: fold SPLIT partials + emit frags
__global__ __launch_bounds__(256) void pool_finish_kernel(
    const double* __restrict__ ppool, double* __restrict__ rest64,
    short* __restrict__ rhf, short* __restrict__ rlf,
    int N, int tpn, int pn, int SPL)
{
  __shared__ double psum[4][64];
  int n = blockIdx.x;
  int tid = threadIdx.x;
  int c = tid & 63, ck = tid >> 6;
  if (n >= N) {  // zero pad rows so argmin frags are defined
    if (tid < 64) {
      int pt = n >> 4, m = n & 15, hf = tid >> 5, q = (tid >> 3) & 3, ii = tid & 7;
      size_t slot = ((size_t)(((pt * 2 + hf) * 64) + q * 16 + m)) * 8 + ii;
      rhf[slot] = 0; rlf[slot] = 0;
    }
    return;
  }
  int ppn = pn * pn;
  int b = n / (tpn * ppn); int r = n % (tpn * ppn);
  int u = r / ppn; r %= ppn; int v = r / pn; int x = r % pn;
  int t0 = (u * 4) / tpn, t1 = ((u + 1) * 4 + tpn - 1) / tpn;
  int h0 = (v * 16) / pn, h1 = ((v + 1) * 16 + pn - 1) / pn;
  int w0 = (x * 16) / pn, w1 = ((x + 1) * 16 + pn - 1) / pn;
  int nt = t1 - t0, nh = h1 - h0, nw = w1 - w0;
  (void)b; (void)t0; (void)h0; (void)w0;
  int q4 = SPL >> 2;
  const double* pp = ppool + ((size_t)n * SPL) * 64 + c;
  double s = 0.0;
  for (int sp = ck * q4; sp < (ck + 1) * q4; sp++) s += pp[(size_t)sp * 64];
  psum[ck][c] = s;
  __syncthreads();
  if (tid < 64) {
    double t = ((psum[0][c] + psum[1][c]) + psum[2][c]) + psum[3][c];
    float wt = 1.f / (float)nt, wh = 1.f / (float)nh, ww = 1.f / (float)nw;
    double rv = t * (double)wt * (double)wh * (double)ww;
    rest64[(size_t)n * 64 + c] = rv;
    float rv32 = (float)rv;
    float hi; short h = bf16rne(rv32, &hi);
    float hi2; short l = bf16rne(rv32 - hi, &hi2);
    int pt = n >> 4, m = n & 15, hf = c >> 5, qq = (c >> 3) & 3, ii = c & 7;
    size_t slot = ((size_t)(((pt * 2 + hf) * 64) + qq * 16 + m)) * 8 + ii;
    rhf[slot] = h; rlf[slot] = l;
  }
}

// ------------------------------------------- argmin pass 1 (bf16 MFMA GEMM)
// Row-partition; A frags (hi+lo) loaded global->VGPR directly (per-lane
// coalesced 16B), no A LDS -> ~33KB LDS -> 4 blocks/CU. 6-MFMA precision.
__global__ __launch_bounds__(256) void argmin_kernel(
    const short* __restrict__ rhf, const short* __restrict__ rlf,
    const short* __restrict__ ehf, const short* __restrict__ elf,
    const float* __restrict__ esq, float4* __restrict__ part,
    int NSpad, int nstripes)
{
  __shared__ short8 Bh[8][2][64];
  __shared__ short8 Bl[8][2][64];
  __shared__ float esql[128];
  int tid = threadIdx.x;
  int pbase = blockIdx.x * 64;
  int ch = blockIdx.y;
  int wv64 = tid & ~63, ln = tid & 63;
  int w = tid >> 6, lane = tid & 63, col = lane & 15;
  const short8* sAH = (const short8*)(rhf + (size_t)pbase * 64);
  const short8* sAL = (const short8*)(rlf + (size_t)pbase * 64);
  short8 ah0 = sAH[(2 * w + 0) * 64 + lane], ah1 = sAH[(2 * w + 1) * 64 + lane];
  short8 al0 = sAL[(2 * w + 0) * 64 + lane], al1 = sAL[(2 * w + 1) * 64 + lane];
  float M1[4], M2[4]; int I1[4];
#pragma unroll
  for (int r = 0; r < 4; r++) { M1[r] = -3.4e38f; M2[r] = -3.4e38f; I1[r] = 0x7fffffff; }
  for (int s = 0; s < nstripes; s++) {
    int j0 = ch * (nstripes * 128) + s * 128;
    __syncthreads();
    {  // B frags: async linear copy
      const short8* sH = (const short8*)(ehf + (size_t)j0 * 64);
      const short8* sL = (const short8*)(elf + (size_t)j0 * 64);
      short8* dH = (short8*)Bh; short8* dL = (short8*)Bl;
#pragma unroll
      for (int it = 0; it < 4; it++) {
        int idx = it * 256 + wv64;
        gl2lds16(sH + idx + ln, dH + idx);
        gl2lds16(sL + idx + ln, dL + idx);
      }
      if (tid < 128) esql[tid] = esq[j0 + tid];
    }
    __syncthreads();
    floatx4 acc[8];
#pragma unroll
    for (int jt = 0; jt < 8; jt++) {
      float c0 = -0.5f * esql[jt * 16 + col];
      acc[jt] = (floatx4){c0, c0, c0, c0};
    }
#pragma unroll
    for (int jt = 0; jt < 8; jt++) {
      short8 bh0 = Bh[jt][0][lane], bl0 = Bl[jt][0][lane];
      short8 bh1 = Bh[jt][1][lane], bl1 = Bl[jt][1][lane];
      acc[jt] = __builtin_amdgcn_mfma_f32_16x16x32_bf16(al0, bh0, acc[jt], 0, 0, 0);
      acc[jt] = __builtin_amdgcn_mfma_f32_16x16x32_bf16(ah0, bl0, acc[jt], 0, 0, 0);
      acc[jt] = __builtin_amdgcn_mfma_f32_16x16x32_bf16(ah0, bh0, acc[jt], 0, 0, 0);
      acc[jt] = __builtin_amdgcn_mfma_f32_16x16x32_bf16(al1, bh1, acc[jt], 0, 0, 0);
      acc[jt] = __builtin_amdgcn_mfma_f32_16x16x32_bf16(ah1, bl1, acc[jt], 0, 0, 0);
      acc[jt] = __builtin_amdgcn_mfma_f32_16x16x32_bf16(ah1, bh1, acc[jt], 0, 0, 0);
    }
#pragma unroll
    for (int jt = 0; jt < 8; jt++) {
      int j = j0 + jt * 16 + col;
#pragma unroll
      for (int r = 0; r < 4; r++) {
        float a = acc[jt][r];   // a = dot - es/2 ; argmax a == argmin d
        bool c = a > M1[r];
        M2[r] = __builtin_amdgcn_fmed3f(a, M1[r], M2[r]);  // M1>=M2 invariant
        M1[r] = fmaxf(a, M1[r]);
        I1[r] = c ? j : I1[r];
      }
    }
  }
#pragma unroll
  for (int off = 1; off < 16; off <<= 1) {
#pragma unroll
    for (int r = 0; r < 4; r++) {
      float o1 = __shfl_xor(M1[r], off);
      int   oi = __shfl_xor(I1[r], off);
      float o2 = __shfl_xor(M2[r], off);
      bool bwin = (o1 > M1[r]) || (o1 == M1[r] && oi < I1[r]);
      float nm2 = bwin ? fmaxf(M1[r], o2) : fmaxf(M2[r], o1);
      if (bwin) { M1[r] = o1; I1[r] = oi; }
      M2[r] = nm2;
    }
  }
  if (col == 0) {
    int quad = lane >> 4;
#pragma unroll
    for (int r = 0; r < 4; r++) {
      int p = pbase + w * 16 + quad * 4 + r;
      part[(size_t)ch * NSpad + p] =
          make_float4(-2.f * M1[r], -2.f * M2[r], __int_as_float(I1[r]), 0.f);
    }
  }
}

// ---------------------------- merge chunks, flag near-ties to global list
__global__ __launch_bounds__(256) void reduce_kernel(
    const float4* __restrict__ part, int* __restrict__ idx_cur,
    float* __restrict__ out_idx, int* flagcnt, int* flaglist,
    int N, int NSpad, int nch)
{
  int n = blockIdx.x * 256 + threadIdx.x;
  if (n >= N) return;
  float m1 = 3.4e38f, m2 = 3.4e38f; int i1 = 0x7fffffff;
  for (int ch = 0; ch < nch; ch++) {
    float4 q = part[(size_t)ch * NSpad + n];
    float o1 = q.x, o2 = q.y; int oi = __float_as_int(q.z);
    bool bwin = (o1 < m1) || (o1 == m1 && oi < i1);
    float nm2 = bwin ? fminf(m1, o2) : fminf(m2, o1);
    if (bwin) { m1 = o1; i1 = oi; }
    m2 = nm2;
  }
  idx_cur[n] = i1;
  out_idx[n] = (float)i1;
  if (m2 - m1 < 0.01f) {
    int pos = atomicAdd(flagcnt, 1);
    flaglist[pos] = n;
  }
}

// -------------------- parallel fp64 rescan, butterfly transpose-sum
__global__ __launch_bounds__(256) void refine_kernel(
    const double* __restrict__ rest64, const float* __restrict__ emb,
    const int* __restrict__ flagcnt, const int* __restrict__ flaglist,
    PBest* __restrict__ pbest)
{
  __shared__ double bmS[4];
  __shared__ int    biS[4];
  int cnt = *flagcnt;
  int ch = blockIdx.y;
  int tid = threadIdx.x;
  int lane = tid & 63, wv = tid >> 6;
  int c4 = lane & 15;
  int g = tid >> 4;          // 16 groups of 16 lanes
  for (int f = blockIdx.x; f < cnt; f += RGRID) {
    int n = flaglist[f];
    const double* rp = rest64 + (size_t)n * 64 + c4 * 4;
    double r0 = rp[0], r1 = rp[1], r2 = rp[2], r3 = rp[3];
    double best = 1e300; int bidx = 0x7fffffff;
    int jb0 = ch * RCODES + g * 128;
#pragma unroll 1
    for (int s16 = 0; s16 < 8; s16++) {
      int jb = jb0 + s16 * 16;
      double a[16];
#pragma unroll
      for (int m = 0; m < 16; m++) {
        float4 ev = *(const float4*)&emb[(size_t)(jb + m) * 64 + c4 * 4];
        double d0 = r0 - (double)ev.x, d1 = r1 - (double)ev.y;
        double d2 = r2 - (double)ev.z, d3 = r3 - (double)ev.w;
        a[m] = (d0 * d0 + d1 * d1) + (d2 * d2 + d3 * d3);
      }
#pragma unroll
      for (int p = 0; p < 4; p++) {
        int s = 1 << p;
        int bit = (lane >> p) & 1;
        int half = 8 >> p;
#pragma unroll
        for (int k = 0; k < half; k++) {
          double lo = a[2 * k], hi = a[2 * k + 1];
          double send = bit ? lo : hi;
          double keep = bit ? hi : lo;
          a[k] = keep + __shfl_xor(send, s);
        }
      }
      double tot = a[0];
      int j = jb + c4;
      if (tot < best) { best = tot; bidx = j; }  // ascending j: first min
    }
#pragma unroll
    for (int off = 1; off < 64; off <<= 1) {
      double ob = __shfl_xor(best, off);
      int    oi = __shfl_xor(bidx, off);
      if (ob < best || (ob == best && oi < bidx)) { best = ob; bidx = oi; }
    }
    if (lane == 0) { bmS[wv] = best; biS[wv] = bidx; }
    __syncthreads();
    if (tid == 0) {
      double b = bmS[0]; int bi2 = biS[0];
      for (int w2 = 1; w2 < 4; w2++) {
        double ob = bmS[w2]; int oi = biS[w2];
        if (ob < b || (ob == b && oi < bi2)) { b = ob; bi2 = oi; }
      }
      pbest[f * RCH + ch].d = b; pbest[f * RCH + ch].idx = bi2;
    }
    __syncthreads();
  }
}

// -------------------------------- fold RCH chunk results per flagged point
__global__ __launch_bounds__(256) void refine_merge_kernel(
    const PBest* __restrict__ pbest, const int* __restrict__ flagcnt,
    const int* __restrict__ flaglist, int* __restrict__ idx_cur,
    float* __restrict__ out_idx)
{
  int f = blockIdx.x * 256 + threadIdx.x;
  if (f >= *flagcnt) return;
  double best = 1e300; int bidx = 0x7fffffff;
  for (int ch = 0; ch < RCH; ch++) {
    double d = pbest[f * RCH + ch].d; int j = pbest[f * RCH + ch].idx;
    if (d < best || (d == best && j < bidx)) { best = d; bidx = j; }
  }
  int n = flaglist[f];
  idx_cur[n] = bidx;
  out_idx[n] = (float)bidx;
}

// ------------------------- trilinear upsample (f32 out)
__device__ inline void axis_map(int L, int outlen, int i, int* j0, int* j1, float* a0, float* a1) {
  if (L == 1) { *j0 = 0; *j1 = 0; *a0 = 1.f; *a1 = 0.f; return; }
  double scale = (double)L / (double)outlen;
  double src = (i + 0.5) * scale - 0.5;
  if (src < 0.0) src = 0.0;
  int i0 = (int)floor(src); if (i0 > L - 1) i0 = L - 1;
  int i1 = i0 + 1; if (i1 > L - 1) i1 = L - 1;
  double wv = src - (double)i0;
  if (i0 == i1) {
    float p = (float)(1.0 - wv), q = (float)wv;
    *a0 = p + q; *a1 = 0.f;
  } else { *a0 = (float)(1.0 - wv); *a1 = (float)wv; }
  *j0 = i0; *j1 = i1;
}

__global__ __launch_bounds__(256) void upsample_kernel(
    const float* __restrict__ emb, const int* __restrict__ idx_cur,
    float* __restrict__ hup, int tpn, int pn)
{
  int e = blockIdx.x * 256 + threadIdx.x;
  int c = e & 63, w = (e >> 6) & 15, h = (e >> 10) & 15, t = (e >> 14) & 3, b = e >> 16;
  int t0, t1, h0, h1, w0, w1; float ta0, ta1, ha0, ha1, wa0, wa1;
  axis_map(tpn, 4, t, &t0, &t1, &ta0, &ta1);
  axis_map(pn, 16, h, &h0, &h1, &ha0, &ha1);
  axis_map(pn, 16, w, &w0, &w1, &wa0, &wa1);
  int ti[2] = {t0, t1}; float ta[2] = {ta0, ta1};
  int hi[2] = {h0, h1}; float ha[2] = {ha0, ha1};
  int wi[2] = {w0, w1}; float wa[2] = {wa0, wa1};
  double val = 0.0;
  for (int a = 0; a < 2; a++)
    for (int bb = 0; bb < 2; bb++)
      for (int cc = 0; cc < 2; cc++) {
        double wgt = (double)ta[a] * (double)ha[bb] * (double)wa[cc];
        if (wgt != 0.0) {
          int code = idx_cur[((b * tpn + ti[a]) * pn + hi[bb]) * pn + wi[cc]];
          val += wgt * (double)emb[(size_t)code * 64 + c];
        }
      }
  hup[e] = (float)val;
}

// --------------------- conv3d partial — fp32, ci-half x co-half blocks
#define WLV   864                 // valid float4 slots per wl buffer
#define WLPAD (WLV * 4 + 128)     // floats per buffer incl. DMA-tail pad
__global__ __launch_bounds__(256) void conv_part_kernel(
    const float* __restrict__ hup, const float* __restrict__ twt,
    float* __restrict__ pacc, int qi)
{
  __shared__ float hl[2][4][3][6][18];               // dbuf halo, 2x5184B
  __shared__ __align__(16) float wl[2][WLPAD];       // dbuf weights (padded)
  int bid = blockIdx.x;
  int coH = bid & 1, s2 = (bid >> 1) & 1, hq = (bid >> 2) & 3, t = (bid >> 4) & 3, b = bid >> 6;
  int tid = threadIdx.x;
  int c4 = tid & 15;         // co_local = c4*2 + {0,1}
  int wq = (tid >> 4) & 3;   // w0 = wq*4
  int th = tid >> 6;         // h = hq*4 + th
  int h = hq * 4 + th, w0 = wq * 4;
  int wv64 = tid & ~63, ln = tid & 63;

  int lofs[6]; int gofs[6]; bool pred[6];
#pragma unroll
  for (int j = 0; j < 6; j++) {
    int i = tid + j * 256;
    bool vs = i < 1296;
    int ii = vs ? i : 0;
    int cc = ii & 3; int jj = ii >> 2;
    int ww = jj % 18; int k = jj / 18;
    int hh = k % 6, tt = k / 6;
    int gt = t - 1 + tt, gh = hq * 4 - 1 + hh, gw = ww - 1;
    bool inb = gt >= 0 && gt < 4 && gh >= 0 && gh < 16 && gw >= 0 && gw < 16;
    lofs[j] = ((cc * 3 + tt) * 6 + hh) * 18 + ww;
    gofs[j] = inb ? ((((b * 4 + gt) * 16 + gh) * 16 + gw) * 64 + cc) : 0;
    pred[j] = vs && inb;
  }
  float* hlf0 = &hl[0][0][0][0][0];
  float* hlf1 = &hl[1][0][0][0][0];

#define STAGE_W(bb, ci0v)                                                      \
  {                                                                            \
    const float4* srcb = (const float4*)twt;                                   \
    float4* dstb = (float4*)wl[bb];                                            \
    _Pragma("unroll")                                                          \
    for (int k2 = 0; k2 < 4; k2++) {                                           \
      int idx = k2 * 256 + wv64;                                               \
      if (idx < WLV) {                                                         \
        int i2 = idx + ln; if (i2 > WLV - 1) i2 = WLV - 1;                     \
        int f4 = i2 & 7; int tc = i2 >> 3;                                     \
        int tap = tc >> 2, cc2 = tc & 3;                                       \
        const float4* g = srcb + ((size_t)((qi * 27 + tap) * 64 + (ci0v) + cc2) * 16 + coH * 8 + f4); \
        gl2lds16(g, dstb + idx);                                               \
      }                                                                        \
    }                                                                          \
  }

  float acc[4][2];
#pragma unroll
  for (int wi = 0; wi < 4; wi++) { acc[wi][0] = 0.f; acc[wi][1] = 0.f; }

  {
    int ci0 = s2 * 32;
    float hreg[6];
#pragma unroll
    for (int j = 0; j < 6; j++) hreg[j] = pred[j] ? hup[gofs[j] + ci0] : 0.f;
    STAGE_W(0, ci0);
#pragma unroll
    for (int j = 0; j < 6; j++)
      if (tid + j * 256 < 1296) hlf0[lofs[j]] = hreg[j];
    __syncthreads();
  }

  int cur = 0;
#pragma unroll 1
  for (int c4i = 0; c4i < 8; c4i++) {
    int nxt = cur ^ 1;
    float hreg[6];
    if (c4i < 7) {
      int ci0n = s2 * 32 + (c4i + 1) * 4;
#pragma unroll
      for (int j = 0; j < 6; j++) hreg[j] = pred[j] ? hup[gofs[j] + ci0n] : 0.f;
      STAGE_W(nxt, ci0n);
    }
    const float* wlc = wl[cur];
#pragma unroll 1
    for (int dtdh = 0; dtdh < 9; dtdh++) {
      int dt = dtdh / 3, dh = dtdh % 3;
#pragma unroll
      for (int cc = 0; cc < 4; cc++) {
        float hv[6];
#pragma unroll
        for (int k = 0; k < 6; k++) hv[k] = hl[cur][cc][dt][th + dh][w0 + k];
#pragma unroll
        for (int dw = 0; dw < 3; dw++) {
          float2 wf = *(const float2*)&wlc[(((dtdh * 3 + dw) * 4 + cc) << 5) + c4 * 2];
#pragma unroll
          for (int wi = 0; wi < 4; wi++) {
            float hvv = hv[wi + dw];
            acc[wi][0] += hvv * wf.x; acc[wi][1] += hvv * wf.y;
          }
        }
      }
    }
    if (c4i < 7) {
      float* hlfn = nxt ? hlf1 : hlf0;
#pragma unroll
      for (int j = 0; j < 6; j++)
        if (tid + j * 256 < 1296) hlfn[lofs[j]] = hreg[j];
    }
    __syncthreads();
    cur = nxt;
  }
#undef STAGE_W

  float* base = &pacc[(size_t)s2 * NELEM +
                      (size_t)((((b * 4 + t) * 16 + h) * 16 + w0) * 64 + coH * 32 + c4 * 2)];
#pragma unroll
  for (int wi = 0; wi < 4; wi++) {
    float2 v = make_float2(acc[wi][0], acc[wi][1]);
    *(float2*)(base + wi * 64) = v;
  }
}

// ------------------- combine partials + bias + 0.5/0.5 mix + accu + sse
__global__ __launch_bounds__(256) void conv_combine_kernel(
    const float* __restrict__ pacc, const float* __restrict__ hup,
    const float* __restrict__ bq, const float* __restrict__ zcl,
    double* __restrict__ accu, double* sse, int qi)
{
  __shared__ double red[256];
  int tid = threadIdx.x;
  int e = blockIdx.x * 256 + tid;
  int co = e & 63;
  double cv = ((double)pacc[e] + (double)pacc[(size_t)NELEM + e]) + (double)bq[qi * 64 + co];
  double hu = (double)hup[e];
  double na = accu[e] + 0.5 * hu + 0.5 * cv;
  accu[e] = na;
  double df = na - (double)zcl[e];
  red[tid] = df * df;
  __syncthreads();
  for (int s = 128; s > 0; s >>= 1) { if (tid < s) red[tid] += red[tid + s]; __syncthreads(); }
  if (tid == 0) atomicAdd(sse, red[0]);
}

// ---------------------------------------------------------------- stats
__global__ __launch_bounds__(256) void bincount_kernel(const int* __restrict__ idx_cur, int* counts) {
  int i = blockIdx.x * 256 + threadIdx.x;
  if (i < NSP) atomicAdd(&counts[idx_cur[i]], 1);
}

__global__ __launch_bounds__(256) void stats_kernel(
    const int* __restrict__ counts, float* __restrict__ usage_out, double* ent, int* usedcnt)
{
  __shared__ double re[256];
  __shared__ int ru[256];
  int j = blockIdx.x * 256 + threadIdx.x;
  int cnt = counts[j];
  double p = (double)cnt / 8192.0;
  usage_out[j] = (float)p;
  re[threadIdx.x] = p * log(p + 1e-10);
  ru[threadIdx.x] = cnt > 0 ? 1 : 0;
  __syncthreads();
  for (int s = 128; s > 0; s >>= 1) {
    if (threadIdx.x < s) { re[threadIdx.x] += re[threadIdx.x + s]; ru[threadIdx.x] += ru[threadIdx.x + s]; }
    __syncthreads();
  }
  if (threadIdx.x == 0) { atomicAdd(ent, re[0]); atomicAdd(usedcnt, ru[0]); }
}

__global__ void final_kernel(const double* sse, const double* ent, const int* usedcnt, float* out) {
  if (threadIdx.x == 0) {
    out[NELEM]     = (float)(*sse * 0.25 / 524288.0 / 10.0);
    out[NELEM + 1] = (float)exp(-*ent);
    out[NELEM + 2] = (float)((double)*usedcnt / 16384.0);
  }
}

// -------- accu [spatial][c] f64 -> out [b][c][t][h][w] f32, LDS transpose
// grid 512 = [b:3][t:2][h:4]; tile 16w x 64c.
__global__ __launch_bounds__(256) void embstT_kernel(
    const double* __restrict__ accu, float* __restrict__ out)
{
  __shared__ float tile[16][65];
  int bid = blockIdx.x;
  int h = bid & 15, t = (bid >> 4) & 3, b = bid >> 6;
  int tid = threadIdx.x;
#pragma unroll
  for (int k = 0; k < 4; k++) {  // read: lane varies c -> 512B contiguous
    int elem = tid + k * 256;
    int w = elem >> 6, c = elem & 63;
    tile[w][c] = (float)accu[(size_t)((((b * 4 + t) * 16 + h) * 16 + w) * 64 + c)];
  }
  __syncthreads();
#pragma unroll
  for (int k = 0; k < 4; k++) {  // write: lane varies w (16) then c -> 4x64B segs
    int elem = tid + k * 256;
    int c = elem >> 4, w = elem & 15;
    out[(size_t)(((b * 64 + c) * 4 + t) * 16 + h) * 16 + w] = tile[w][c];
  }
}

// ---------------------------------------------------------------- launch
extern "C" void kernel_launch(void* const* d_in, const int* in_sizes, int n_in,
                              void* d_out, int out_size, void* d_ws, size_t ws_size,
                              hipStream_t stream) {
  static const int T_PN_h[10] = {1, 1, 2, 2, 2, 4, 4, 4, 4, 4};
  static const int V_PN_h[10] = {1, 2, 3, 4, 5, 6, 8, 10, 13, 16};
  // qi from bit-exact fp64 emulation of np.linspace+argmin (ties: si=2->1, si=7->3)
  static const int QI_h[10]   = {0, 0, 1, 1, 1, 2, 2, 3, 3, 3};
  static const int NS_h[10]   = {8, 32, 144, 256, 400, 1152, 2048, 3200, 5408, 8192};
  static const int OB_h[10]   = {540675, 540683, 540715, 540859, 541115,
                                 541515, 542667, 544715, 547915, 553323};
  static const int NCH_h[10]  = {64, 64, 64, 64, 64, 32, 32, 32, 16, 16};
  static const int SPL_h[10]  = {128, 32, 8, 4, 4, 1, 1, 1, 1, 1};

  const float* z   = (const float*)d_in[0];
  const float* emb = (const float*)d_in[1];
  const float* Wq  = (const float*)d_in[2];
  const float* bq  = (const float*)d_in[3];
  float* out = (float*)d_out;
  char* ws = (char*)d_ws;

  double* accu    = (double*)(ws + WS_ACCU);
  float*  hup     = (float*)(ws + WS_HUP);
  double* rest64  = (double*)(ws + WS_REST64);
  float*  pacc    = (float*)(ws + WS_PACC);
  float4* part    = (float4*)(ws + WS_PART);
  PBest*  pbest   = (PBest*)(ws + WS_PART);
  double* ppool   = (double*)(ws + WS_PART);
  float*  zcl     = (float*)(ws + WS_ZCL);
  short*  ehf     = (short*)(ws + WS_EHF);
  short*  elf     = (short*)(ws + WS_ELF);
  float*  esq     = (float*)(ws + WS_ESQ);
  float*  twt     = (float*)(ws + WS_TWT);
  int*    idx_cur = (int*)(ws + WS_IDX);
  int*    counts  = (int*)(ws + WS_CNT);
  int*    flaglist= (int*)(ws + WS_FLAGL);
  int*    flagcnt = (int*)(ws + WS_FLAGC);
  double* sse     = (double*)(ws + WS_SSE);
  double* ent     = (double*)(ws + WS_ENT);
  int*    usedcnt = (int*)(ws + WS_USED);
  short*  rhf     = (short*)(ws + WS_RHF);
  short*  rlf     = (short*)(ws + WS_RLF);

  prep_kernel<<<8001, 256, 0, stream>>>(z, emb, Wq, accu, ehf, elf, esq, twt,
                                        counts, flagcnt, sse, ent, usedcnt);
  zclT_kernel<<<512, 256, 0, stream>>>(z, zcl);

  for (int si = 0; si < 10; si++) {
    int tpn = T_PN_h[si], pn = V_PN_h[si], N = NS_h[si];
    int NSpad = (N + 63) & ~63;
    int nch = NCH_h[si];
    int nstripes = (NCODES / nch) / 128;
    int SPL = SPL_h[si];
    if (SPL > 1) {
      dim3 pg(N, SPL);
      pool_part_kernel<<<pg, 256, 0, stream>>>(zcl, accu, ppool, N, tpn, pn, SPL);
      pool_finish_kernel<<<NSpad, 256, 0, stream>>>(ppool, rest64, rhf, rlf, N, tpn, pn, SPL);
    } else {
      pool_kernel<<<NSpad, 256, 0, stream>>>(zcl, accu, rest64, rhf, rlf, N, tpn, pn);
    }
    dim3 ag(NSpad / 64, nch);
    argmin_kernel<<<ag, 256, 0, stream>>>(rhf, rlf, ehf, elf, esq, part, NSpad, nstripes);
    reduce_kernel<<<(N + 255) / 256, 256, 0, stream>>>(part, idx_cur, out + OB_h[si],
                                                       flagcnt + si, flaglist, N, NSpad, nch);
    dim3 rg(RGRID, RCH);
    refine_kernel<<<rg, 256, 0, stream>>>(rest64, emb, flagcnt + si, flaglist, pbest);
    refine_merge_kernel<<<(N + 255) / 256, 256, 0, stream>>>(pbest, flagcnt + si, flaglist,
                                                             idx_cur, out + OB_h[si]);
    upsample_kernel<<<NELEM / 256, 256, 0, stream>>>(emb, idx_cur, hup, tpn, pn);
    conv_part_kernel<<<512, 256, 0, stream>>>(hup, twt, pacc, QI_h[si]);
    conv_combine_kernel<<<NELEM / 256, 256, 0, stream>>>(pacc, hup, bq, zcl, accu, sse, QI_h[si]);
  }

  bincount_kernel<<<32, 256, 0, stream>>>(idx_cur, counts);
  stats_kernel<<<64, 256, 0, stream>>>(counts, out + 524291, ent, usedcnt);
  final_kernel<<<1, 64, 0, stream>>>(sse, ent, usedcnt, out);
  embstT_kernel<<<512, 256, 0, stream>>>(accu, out);
}

// Round 11
// 1462.324 us; speedup vs baseline: 1.1218x; 1.1218x over previous
//
#include <hip/hip_runtime.h>
#include <math.h>

// MultiScaleCodebook on MI355X — round 25: r23 base + two micro-fixes.
// r24 post-mortem: zclT/embstT/RGRID changes were neutral-to-negative
// (1640 vs 1597) — z/accu strided reads were already L2-absorbed; reverted
// to r23. This round: (1) pool@si9 (M==1, a pure copy) -> flat kernel,
// all 256 threads active, no LDS/barrier, bit-identical rest64/frags;
// (2) conv_combine: grid 512 x 4 elems/thread, wave shfl reduce + 1 atomic
// per block (was 8-barrier tree + 2048 same-address atomics). sse order
// change ~1e-15 on a tolerance-checked scalar. All else = r23 (champion).

#define NCODES 16384
#define NELEM  524288   // 8*64*4*16*16
#define NSP    8192     // 8*4*16*16

#define RCH    8        // refine chunks
#define RCODES (NCODES / RCH)   // 2048 codes per chunk

#define WS_ACCU   0ul
#define WS_HUP    4194304ul    // hup f32, 2MB used of 4MB
#define WS_REST64 8388608ul    // rest64 f64 4MB [8388608,12582912)
#define WS_PACC   8388608ul    // pacc f32[2][NELEM] 4MB aliases rest64
#define WS_PART   12582912ul   // <=2MB used; ppool + refine pbest alias this
#define WS_ZCL    16777216ul
#define WS_EHF    18874368ul   // emb bf16-hi frags, 2MB
#define WS_ELF    20971520ul   // emb bf16-lo frags, 2MB
#define WS_ESQ    23068672ul
#define WS_TWT    23134208ul
#define WS_IDX    24903680ul
#define WS_CNT    24936448ul
#define WS_FLAGL  25001984ul
#define WS_FLAGC  25034752ul
#define WS_SSE    25034816ul
#define WS_ENT    25034824ul
#define WS_USED   25034832ul
#define WS_RHF    25034848ul   // rest bf16-hi frags, 1MB
#define WS_RLF    26083424ul   // rest bf16-lo frags, 1MB

typedef __attribute__((ext_vector_type(8))) short short8;
typedef __attribute__((ext_vector_type(4))) float floatx4;

struct PBest { double d; int idx; int pad; };

// async 16B global->LDS: lds dest = wave-uniform base + lane*16
__device__ __forceinline__ void gl2lds16(const void* g, void* l) {
  __builtin_amdgcn_global_load_lds(
      (const __attribute__((address_space(1))) unsigned int*)g,
      (__attribute__((address_space(3))) unsigned int*)l, 16, 0, 0);
}

// round-to-nearest-even float -> bf16; also returns hi as float
__device__ inline short bf16rne(float f, float* hi) {
  unsigned u = __float_as_uint(f);
  unsigned r = (u + 0x7FFFu + ((u >> 16) & 1u)) >> 16;
  *hi = __uint_as_float(r << 16);
  return (short)r;
}

// ---------------------------------------------------------------- prep
__global__ __launch_bounds__(256) void prep_kernel(
    const float* __restrict__ z, const float* __restrict__ emb, const float* __restrict__ Wq,
    double* __restrict__ accu, float* __restrict__ zcl,
    short* __restrict__ ehf, short* __restrict__ elf,
    float* __restrict__ esq, float* __restrict__ twt,
    int* __restrict__ counts, int* __restrict__ flagcnt,
    double* sse, double* ent, int* usedcnt)
{
  int i = blockIdx.x * 256 + threadIdx.x;
  if (i < NELEM) { accu[i] = 0.0; return; }
  i -= NELEM;
  if (i < NELEM) {  // z [B,C,T,H,W] -> zcl [B,T,H,W,C]
    int c = i & 63, w = (i >> 6) & 15, h = (i >> 10) & 15, t = (i >> 14) & 3, b = i >> 16;
    zcl[i] = z[(((b * 64 + c) * 4 + t) * 16 + h) * 16 + w];
    return;
  }
  i -= NELEM;
  if (i < NCODES * 64) {  // emb -> bf16 split, MFMA B-frag order
    int j = i >> 6, c = i & 63;
    float v = emb[i];
    float hi; short h = bf16rne(v, &hi);
    float hi2; short l = bf16rne(v - hi, &hi2);
    int jt = j >> 4, nn = j & 15, hf = c >> 5, q = (c >> 3) & 3, ii = c & 7;
    size_t slot = ((size_t)(((jt * 2 + hf) * 64) + q * 16 + nn)) * 8 + ii;
    ehf[slot] = h; elf[slot] = l;
    return;
  }
  i -= NCODES * 64;
  if (i < NCODES) {  // e_sq fp32 (ranking only; refine is fp64)
    float s = 0.f;
    for (int c = 0; c < 64; c++) { float v = emb[i * 64 + c]; s += v * v; }
    esq[i] = s; return;
  }
  i -= NCODES;
  if (i < 442368) {  // twt[qi][tap][ci][co] = Wq[qi][co][ci][tap]
    int qi = i / 110592; int r = i % 110592;
    int tap = r >> 12; int ci = (r >> 6) & 63; int co = r & 63;
    twt[i] = Wq[((qi * 64 + co) * 64 + ci) * 27 + tap];
    return;
  }
  i -= 442368;
  if (i < NCODES) { counts[i] = 0; return; }
  i -= NCODES;
  if (i < 16) {
    if (i < 10) flagcnt[i] = 0;
    else if (i == 10) *sse = 0.0;
    else if (i == 11) *ent = 0.0;
    else if (i == 12) *usedcnt = 0;
  }
}

// ------------------------------------------- pool (area) + frag emit
// single-stage path (SPLIT==1 scales, si5..si8)
__global__ __launch_bounds__(256) void pool_kernel(
    const float* __restrict__ zcl, const double* __restrict__ accu,
    double* __restrict__ rest64, short* __restrict__ rhf, short* __restrict__ rlf,
    int N, int tpn, int pn)
{
  __shared__ double psum[4][64];
  int n = blockIdx.x;
  int tid = threadIdx.x;
  int c = tid & 63, ck = tid >> 6;
  if (n >= N) {  // zero pad rows so argmin frags are defined
    if (tid < 64) {
      int pt = n >> 4, m = n & 15, hf = tid >> 5, q = (tid >> 3) & 3, ii = tid & 7;
      size_t slot = ((size_t)(((pt * 2 + hf) * 64) + q * 16 + m)) * 8 + ii;
      rhf[slot] = 0; rlf[slot] = 0;
    }
    return;
  }
  int ppn = pn * pn;
  int b = n / (tpn * ppn); int r = n % (tpn * ppn);
  int u = r / ppn; r %= ppn; int v = r / pn; int x = r % pn;
  int t0 = (u * 4) / tpn, t1 = ((u + 1) * 4 + tpn - 1) / tpn;
  int h0 = (v * 16) / pn, h1 = ((v + 1) * 16 + pn - 1) / pn;
  int w0 = (x * 16) / pn, w1 = ((x + 1) * 16 + pn - 1) / pn;
  int nt = t1 - t0, nh = h1 - h0, nw = w1 - w0;
  int M = nt * nh * nw;
  int chunk = (M + 3) >> 2;
  int m0 = ck * chunk; int m1 = m0 + chunk; if (m1 > M) m1 = M;
  double s = 0.0;
  if (m0 < m1) {
    int tmp = m0 / nw; int wi = m0 - tmp * nw;
    int ti = tmp / nh; int hi = tmp - ti * nh;
    for (int m = m0; m < m1; m++) {
      size_t off = (size_t)((((b * 4 + t0 + ti) * 16 + h0 + hi) * 16 + w0 + wi) * 64 + c);
      s += (double)zcl[off] - accu[off];
      if (++wi == nw) { wi = 0; if (++hi == nh) { hi = 0; ++ti; } }
    }
  }
  psum[ck][c] = s;
  __syncthreads();
  if (tid < 64) {
    double t = ((psum[0][c] + psum[1][c]) + psum[2][c]) + psum[3][c];
    float wt = 1.f / (float)nt, wh = 1.f / (float)nh, ww = 1.f / (float)nw;
    double rv = t * (double)wt * (double)wh * (double)ww;
    rest64[(size_t)n * 64 + c] = rv;
    float rv32 = (float)rv;
    float hi; short h = bf16rne(rv32, &hi);
    float hi2; short l = bf16rne(rv32 - hi, &hi2);
    int pt = n >> 4, m = n & 15, hf = c >> 5, q = (c >> 3) & 3, ii = c & 7;
    size_t slot = ((size_t)(((pt * 2 + hf) * 64) + q * 16 + m)) * 8 + ii;
    rhf[slot] = h; rlf[slot] = l;
  }
}

// ------------------- pool flat path (si9: tpn=4, pn=16, M==1 — pure copy)
// rest = zcl - accu elementwise; bit-identical to pool_kernel at M==1
// (single-element sum, x1.0 weights exact). All threads active, no LDS.
__global__ __launch_bounds__(256) void pool_flat_kernel(
    const float* __restrict__ zcl, const double* __restrict__ accu,
    double* __restrict__ rest64, short* __restrict__ rhf, short* __restrict__ rlf)
{
  int e = blockIdx.x * 256 + threadIdx.x;
  int n = e >> 6, c = e & 63;
  double rv = (double)zcl[e] - accu[e];
  rest64[e] = rv;
  float rv32 = (float)rv;
  float hi; short h = bf16rne(rv32, &hi);
  float hi2; short l = bf16rne(rv32 - hi, &hi2);
  int pt = n >> 4, m = n & 15, hf = c >> 5, q = (c >> 3) & 3, ii = c & 7;
  size_t slot = ((size_t)(((pt * 2 + hf) * 64) + q * 16 + m)) * 8 + ii;
  rhf[slot] = h; rlf[slot] = l;
}

// ------------------- pool stage 1: split-K partials (small-N scales)
__global__ __launch_bounds__(256) void pool_part_kernel(
    const float* __restrict__ zcl, const double* __restrict__ accu,
    double* __restrict__ ppool, int N, int tpn, int pn, int SPL)
{
  __shared__ double psum[4][64];
  int n = blockIdx.x;
  int sp = blockIdx.y;
  int tid = threadIdx.x;
  int c = tid & 63, ck = tid >> 6;
  int ppn = pn * pn;
  int b = n / (tpn * ppn); int r = n % (tpn * ppn);
  int u = r / ppn; r %= ppn; int v = r / pn; int x = r % pn;
  int t0 = (u * 4) / tpn, t1 = ((u + 1) * 4 + tpn - 1) / tpn;
  int h0 = (v * 16) / pn, h1 = ((v + 1) * 16 + pn - 1) / pn;
  int w0 = (x * 16) / pn, w1 = ((x + 1) * 16 + pn - 1) / pn;
  int nt = t1 - t0, nh = h1 - h0, nw = w1 - w0;
  int M = nt * nh * nw;
  int C = SPL * 4;
  int chunk = (M + C - 1) / C;
  int m0 = (sp * 4 + ck) * chunk; int m1 = m0 + chunk;
  if (m0 > M) m0 = M;
  if (m1 > M) m1 = M;
  double s = 0.0;
  if (m0 < m1) {
    int tmp = m0 / nw; int wi = m0 - tmp * nw;
    int ti = tmp / nh; int hi = tmp - ti * nh;
    for (int m = m0; m < m1; m++) {
      size_t off = (size_t)((((b * 4 + t0 + ti) * 16 + h0 + hi) * 16 + w0 + wi) * 64 + c);
      s += (double)zcl[off] - accu[off];
      if (++wi == nw) { wi = 0; if (++hi == nh) { hi = 0; ++ti; } }
    }
  }
  psum[ck][c] = s;
  __syncthreads();
  if (tid < 64) {
    double t = ((psum[0][c] + psum[1][c]) + psum[2][c]) + psum[3][c];
    ppool[((size_t)n * SPL + sp) * 64 + c] = t;
  }
}

// ------------------- pool stage 2: fold SPLIT partials + emit frags
__global__ __launch_bounds__(256) void pool_finish_kernel(
    const double* __restrict__ ppool, double* __restrict__ rest64,
    short* __restrict__ rhf, short* __restrict__ rlf,
    int N, int tpn, int pn, int SPL)
{
  __shared__ double psum[4][64];
  int n = blockIdx.x;
  int tid = threadIdx.x;
  int c = tid & 63, ck = tid >> 6;
  if (n >= N) {  // zero pad rows so argmin frags are defined
    if (tid < 64) {
      int pt = n >> 4, m = n & 15, hf = tid >> 5, q = (tid >> 3) & 3, ii = tid & 7;
      size_t slot = ((size_t)(((pt * 2 + hf) * 64) + q * 16 + m)) * 8 + ii;
      rhf[slot] = 0; rlf[slot] = 0;
    }
    return;
  }
  int ppn = pn * pn;
  int b = n / (tpn * ppn); int r = n % (tpn * ppn);
  int u = r / ppn; r %= ppn; int v = r / pn; int x = r % pn;
  int t0 = (u * 4) / tpn, t1 = ((u + 1) * 4 + tpn - 1) / tpn;
  int h0 = (v * 16) / pn, h1 = ((v + 1) * 16 + pn - 1) / pn;
  int w0 = (x * 16) / pn, w1 = ((x + 1) * 16 + pn - 1) / pn;
  int nt = t1 - t0, nh = h1 - h0, nw = w1 - w0;
  (void)b; (void)t0; (void)h0; (void)w0;
  int q4 = SPL >> 2;
  const double* pp = ppool + ((size_t)n * SPL) * 64 + c;
  double s = 0.0;
  for (int sp = ck * q4; sp < (ck + 1) * q4; sp++) s += pp[(size_t)sp * 64];
  psum[ck][c] = s;
  __syncthreads();
  if (tid < 64) {
    double t = ((psum[0][c] + psum[1][c]) + psum[2][c]) + psum[3][c];
    float wt = 1.f / (float)nt, wh = 1.f / (float)nh, ww = 1.f / (float)nw;
    double rv = t * (double)wt * (double)wh * (double)ww;
    rest64[(size_t)n * 64 + c] = rv;
    float rv32 = (float)rv;
    float hi; short h = bf16rne(rv32, &hi);
    float hi2; short l = bf16rne(rv32 - hi, &hi2);
    int pt = n >> 4, m = n & 15, hf = c >> 5, qq = (c >> 3) & 3, ii = c & 7;
    size_t slot = ((size_t)(((pt * 2 + hf) * 64) + qq * 16 + m)) * 8 + ii;
    rhf[slot] = h; rlf[slot] = l;
  }
}

// ------------------------------------------- argmin pass 1 (bf16 MFMA GEMM)
// Row-partition; A frags (hi+lo) loaded global->VGPR directly (per-lane
// coalesced 16B), no A LDS -> ~33KB LDS -> 4 blocks/CU. 6-MFMA precision.
__global__ __launch_bounds__(256) void argmin_kernel(
    const short* __restrict__ rhf, const short* __restrict__ rlf,
    const short* __restrict__ ehf, const short* __restrict__ elf,
    const float* __restrict__ esq, float4* __restrict__ part,
    int NSpad, int nstripes)
{
  __shared__ short8 Bh[8][2][64];
  __shared__ short8 Bl[8][2][64];
  __shared__ float esql[128];
  int tid = threadIdx.x;
  int pbase = blockIdx.x * 64;
  int ch = blockIdx.y;
  int wv64 = tid & ~63, ln = tid & 63;
  int w = tid >> 6, lane = tid & 63, col = lane & 15;
  const short8* sAH = (const short8*)(rhf + (size_t)pbase * 64);
  const short8* sAL = (const short8*)(rlf + (size_t)pbase * 64);
  short8 ah0 = sAH[(2 * w + 0) * 64 + lane], ah1 = sAH[(2 * w + 1) * 64 + lane];
  short8 al0 = sAL[(2 * w + 0) * 64 + lane], al1 = sAL[(2 * w + 1) * 64 + lane];
  float M1[4], M2[4]; int I1[4];
#pragma unroll
  for (int r = 0; r < 4; r++) { M1[r] = -3.4e38f; M2[r] = -3.4e38f; I1[r] = 0x7fffffff; }
  for (int s = 0; s < nstripes; s++) {
    int j0 = ch * (nstripes * 128) + s * 128;
    __syncthreads();
    {  // B frags: async linear copy
      const short8* sH = (const short8*)(ehf + (size_t)j0 * 64);
      const short8* sL = (const short8*)(elf + (size_t)j0 * 64);
      short8* dH = (short8*)Bh; short8* dL = (short8*)Bl;
#pragma unroll
      for (int it = 0; it < 4; it++) {
        int idx = it * 256 + wv64;
        gl2lds16(sH + idx + ln, dH + idx);
        gl2lds16(sL + idx + ln, dL + idx);
      }
      if (tid < 128) esql[tid] = esq[j0 + tid];
    }
    __syncthreads();
    floatx4 acc[8];
#pragma unroll
    for (int jt = 0; jt < 8; jt++) {
      float c0 = -0.5f * esql[jt * 16 + col];
      acc[jt] = (floatx4){c0, c0, c0, c0};
    }
#pragma unroll
    for (int jt = 0; jt < 8; jt++) {
      short8 bh0 = Bh[jt][0][lane], bl0 = Bl[jt][0][lane];
      short8 bh1 = Bh[jt][1][lane], bl1 = Bl[jt][1][lane];
      acc[jt] = __builtin_amdgcn_mfma_f32_16x16x32_bf16(al0, bh0, acc[jt], 0, 0, 0);
      acc[jt] = __builtin_amdgcn_mfma_f32_16x16x32_bf16(ah0, bl0, acc[jt], 0, 0, 0);
      acc[jt] = __builtin_amdgcn_mfma_f32_16x16x32_bf16(ah0, bh0, acc[jt], 0, 0, 0);
      acc[jt] = __builtin_amdgcn_mfma_f32_16x16x32_bf16(al1, bh1, acc[jt], 0, 0, 0);
      acc[jt] = __builtin_amdgcn_mfma_f32_16x16x32_bf16(ah1, bl1, acc[jt], 0, 0, 0);
      acc[jt] = __builtin_amdgcn_mfma_f32_16x16x32_bf16(ah1, bh1, acc[jt], 0, 0, 0);
    }
#pragma unroll
    for (int jt = 0; jt < 8; jt++) {
      int j = j0 + jt * 16 + col;
#pragma unroll
      for (int r = 0; r < 4; r++) {
        float a = acc[jt][r];   // a = dot - es/2 ; argmax a == argmin d
        bool c = a > M1[r];
        M2[r] = __builtin_amdgcn_fmed3f(a, M1[r], M2[r]);  // M1>=M2 invariant
        M1[r] = fmaxf(a, M1[r]);
        I1[r] = c ? j : I1[r];
      }
    }
  }
#pragma unroll
  for (int off = 1; off < 16; off <<= 1) {
#pragma unroll
    for (int r = 0; r < 4; r++) {
      float o1 = __shfl_xor(M1[r], off);
      int   oi = __shfl_xor(I1[r], off);
      float o2 = __shfl_xor(M2[r], off);
      bool bwin = (o1 > M1[r]) || (o1 == M1[r] && oi < I1[r]);
      float nm2 = bwin ? fmaxf(M1[r], o2) : fmaxf(M2[r], o1);
      if (bwin) { M1[r] = o1; I1[r] = oi; }
      M2[r] = nm2;
    }
  }
  if (col == 0) {
    int quad = lane >> 4;
#pragma unroll
    for (int r = 0; r < 4; r++) {
      int p = pbase + w * 16 + quad * 4 + r;
      part[(size_t)ch * NSpad + p] =
          make_float4(-2.f * M1[r], -2.f * M2[r], __int_as_float(I1[r]), 0.f);
    }
  }
}

// ---------------------------- merge chunks, flag near-ties to global list
__global__ __launch_bounds__(256) void reduce_kernel(
    const float4* __restrict__ part, int* __restrict__ idx_cur,
    float* __restrict__ out_idx, int* flagcnt, int* flaglist,
    int N, int NSpad, int nch)
{
  int n = blockIdx.x * 256 + threadIdx.x;
  if (n >= N) return;
  float m1 = 3.4e38f, m2 = 3.4e38f; int i1 = 0x7fffffff;
  for (int ch = 0; ch < nch; ch++) {
    float4 q = part[(size_t)ch * NSpad + n];
    float o1 = q.x, o2 = q.y; int oi = __float_as_int(q.z);
    bool bwin = (o1 < m1) || (o1 == m1 && oi < i1);
    float nm2 = bwin ? fminf(m1, o2) : fminf(m2, o1);
    if (bwin) { m1 = o1; i1 = oi; }
    m2 = nm2;
  }
  idx_cur[n] = i1;
  out_idx[n] = (float)i1;
  if (m2 - m1 < 0.01f) {
    int pos = atomicAdd(flagcnt, 1);
    flaglist[pos] = n;
  }
}

// -------------------- parallel fp64 rescan, butterfly transpose-sum (r18)
__global__ __launch_bounds__(256) void refine_kernel(
    const double* __restrict__ rest64, const float* __restrict__ emb,
    const int* __restrict__ flagcnt, const int* __restrict__ flaglist,
    PBest* __restrict__ pbest)
{
  __shared__ double bmS[4];
  __shared__ int    biS[4];
  int cnt = *flagcnt;
  int ch = blockIdx.y;
  int tid = threadIdx.x;
  int lane = tid & 63, wv = tid >> 6;
  int c4 = lane & 15;
  int g = tid >> 4;          // 16 groups of 16 lanes
  for (int f = blockIdx.x; f < cnt; f += 1024) {
    int n = flaglist[f];
    const double* rp = rest64 + (size_t)n * 64 + c4 * 4;
    double r0 = rp[0], r1 = rp[1], r2 = rp[2], r3 = rp[3];
    double best = 1e300; int bidx = 0x7fffffff;
    int jb0 = ch * RCODES + g * 128;
#pragma unroll 1
    for (int s16 = 0; s16 < 8; s16++) {
      int jb = jb0 + s16 * 16;
      double a[16];
#pragma unroll
      for (int m = 0; m < 16; m++) {
        float4 ev = *(const float4*)&emb[(size_t)(jb + m) * 64 + c4 * 4];
        double d0 = r0 - (double)ev.x, d1 = r1 - (double)ev.y;
        double d2 = r2 - (double)ev.z, d3 = r3 - (double)ev.w;
        a[m] = (d0 * d0 + d1 * d1) + (d2 * d2 + d3 * d3);
      }
#pragma unroll
      for (int p = 0; p < 4; p++) {
        int s = 1 << p;
        int bit = (lane >> p) & 1;
        int half = 8 >> p;
#pragma unroll
        for (int k = 0; k < half; k++) {
          double lo = a[2 * k], hi = a[2 * k + 1];
          double send = bit ? lo : hi;
          double keep = bit ? hi : lo;
          a[k] = keep + __shfl_xor(send, s);
        }
      }
      double tot = a[0];
      int j = jb + c4;
      if (tot < best) { best = tot; bidx = j; }  // ascending j: first min
    }
#pragma unroll
    for (int off = 1; off < 64; off <<= 1) {
      double ob = __shfl_xor(best, off);
      int    oi = __shfl_xor(bidx, off);
      if (ob < best || (ob == best && oi < bidx)) { best = ob; bidx = oi; }
    }
    if (lane == 0) { bmS[wv] = best; biS[wv] = bidx; }
    __syncthreads();
    if (tid == 0) {
      double b = bmS[0]; int bi2 = biS[0];
      for (int w2 = 1; w2 < 4; w2++) {
        double ob = bmS[w2]; int oi = biS[w2];
        if (ob < b || (ob == b && oi < bi2)) { b = ob; bi2 = oi; }
      }
      pbest[f * RCH + ch].d = b; pbest[f * RCH + ch].idx = bi2;
    }
    __syncthreads();
  }
}

// -------------------------------- fold RCH chunk results per flagged point
__global__ __launch_bounds__(256) void refine_merge_kernel(
    const PBest* __restrict__ pbest, const int* __restrict__ flagcnt,
    const int* __restrict__ flaglist, int* __restrict__ idx_cur,
    float* __restrict__ out_idx)
{
  int f = blockIdx.x * 256 + threadIdx.x;
  if (f >= *flagcnt) return;
  double best = 1e300; int bidx = 0x7fffffff;
  for (int ch = 0; ch < RCH; ch++) {
    double d = pbest[f * RCH + ch].d; int j = pbest[f * RCH + ch].idx;
    if (d < best || (d == best && j < bidx)) { best = d; bidx = j; }
  }
  int n = flaglist[f];
  idx_cur[n] = bidx;
  out_idx[n] = (float)bidx;
}

// ------------------------- trilinear upsample (f32 out)
__device__ inline void axis_map(int L, int outlen, int i, int* j0, int* j1, float* a0, float* a1) {
  if (L == 1) { *j0 = 0; *j1 = 0; *a0 = 1.f; *a1 = 0.f; return; }
  double scale = (double)L / (double)outlen;
  double src = (i + 0.5) * scale - 0.5;
  if (src < 0.0) src = 0.0;
  int i0 = (int)floor(src); if (i0 > L - 1) i0 = L - 1;
  int i1 = i0 + 1; if (i1 > L - 1) i1 = L - 1;
  double wv = src - (double)i0;
  if (i0 == i1) {
    float p = (float)(1.0 - wv), q = (float)wv;
    *a0 = p + q; *a1 = 0.f;
  } else { *a0 = (float)(1.0 - wv); *a1 = (float)wv; }
  *j0 = i0; *j1 = i1;
}

__global__ __launch_bounds__(256) void upsample_kernel(
    const float* __restrict__ emb, const int* __restrict__ idx_cur,
    float* __restrict__ hup, int tpn, int pn)
{
  int e = blockIdx.x * 256 + threadIdx.x;
  int c = e & 63, w = (e >> 6) & 15, h = (e >> 10) & 15, t = (e >> 14) & 3, b = e >> 16;
  int t0, t1, h0, h1, w0, w1; float ta0, ta1, ha0, ha1, wa0, wa1;
  axis_map(tpn, 4, t, &t0, &t1, &ta0, &ta1);
  axis_map(pn, 16, h, &h0, &h1, &ha0, &ha1);
  axis_map(pn, 16, w, &w0, &w1, &wa0, &wa1);
  int ti[2] = {t0, t1}; float ta[2] = {ta0, ta1};
  int hi[2] = {h0, h1}; float ha[2] = {ha0, ha1};
  int wi[2] = {w0, w1}; float wa[2] = {wa0, wa1};
  double val = 0.0;
  for (int a = 0; a < 2; a++)
    for (int bb = 0; bb < 2; bb++)
      for (int cc = 0; cc < 2; cc++) {
        double wgt = (double)ta[a] * (double)ha[bb] * (double)wa[cc];
        if (wgt != 0.0) {
          int code = idx_cur[((b * tpn + ti[a]) * pn + hi[bb]) * pn + wi[cc]];
          val += wgt * (double)emb[(size_t)code * 64 + c];
        }
      }
  hup[e] = (float)val;
}

// --------------------- conv3d partial — fp32, ci-half x co-half blocks
#define WLV   864                 // valid float4 slots per wl buffer
#define WLPAD (WLV * 4 + 128)     // floats per buffer incl. DMA-tail pad
__global__ __launch_bounds__(256) void conv_part_kernel(
    const float* __restrict__ hup, const float* __restrict__ twt,
    float* __restrict__ pacc, int qi)
{
  __shared__ float hl[2][4][3][6][18];               // dbuf halo, 2x5184B
  __shared__ __align__(16) float wl[2][WLPAD];       // dbuf weights (padded)
  int bid = blockIdx.x;
  int coH = bid & 1, s2 = (bid >> 1) & 1, hq = (bid >> 2) & 3, t = (bid >> 4) & 3, b = bid >> 6;
  int tid = threadIdx.x;
  int c4 = tid & 15;         // co_local = c4*2 + {0,1}
  int wq = (tid >> 4) & 3;   // w0 = wq*4
  int th = tid >> 6;         // h = hq*4 + th
  int h = hq * 4 + th, w0 = wq * 4;
  int wv64 = tid & ~63, ln = tid & 63;

  int lofs[6]; int gofs[6]; bool pred[6];
#pragma unroll
  for (int j = 0; j < 6; j++) {
    int i = tid + j * 256;
    bool vs = i < 1296;
    int ii = vs ? i : 0;
    int cc = ii & 3; int jj = ii >> 2;
    int ww = jj % 18; int k = jj / 18;
    int hh = k % 6, tt = k / 6;
    int gt = t - 1 + tt, gh = hq * 4 - 1 + hh, gw = ww - 1;
    bool inb = gt >= 0 && gt < 4 && gh >= 0 && gh < 16 && gw >= 0 && gw < 16;
    lofs[j] = ((cc * 3 + tt) * 6 + hh) * 18 + ww;
    gofs[j] = inb ? ((((b * 4 + gt) * 16 + gh) * 16 + gw) * 64 + cc) : 0;
    pred[j] = vs && inb;
  }
  float* hlf0 = &hl[0][0][0][0][0];
  float* hlf1 = &hl[1][0][0][0][0];

#define STAGE_W(bb, ci0v)                                                      \
  {                                                                            \
    const float4* srcb = (const float4*)twt;                                   \
    float4* dstb = (float4*)wl[bb];                                            \
    _Pragma("unroll")                                                          \
    for (int k2 = 0; k2 < 4; k2++) {                                           \
      int idx = k2 * 256 + wv64;                                               \
      if (idx < WLV) {                                                         \
        int i2 = idx + ln; if (i2 > WLV - 1) i2 = WLV - 1;                     \
        int f4 = i2 & 7; int tc = i2 >> 3;                                     \
        int tap = tc >> 2, cc2 = tc & 3;                                       \
        const float4* g = srcb + ((size_t)((qi * 27 + tap) * 64 + (ci0v) + cc2) * 16 + coH * 8 + f4); \
        gl2lds16(g, dstb + idx);                                               \
      }                                                                        \
    }                                                                          \
  }

  float acc[4][2];
#pragma unroll
  for (int wi = 0; wi < 4; wi++) { acc[wi][0] = 0.f; acc[wi][1] = 0.f; }

  {
    int ci0 = s2 * 32;
    float hreg[6];
#pragma unroll
    for (int j = 0; j < 6; j++) hreg[j] = pred[j] ? hup[gofs[j] + ci0] : 0.f;
    STAGE_W(0, ci0);
#pragma unroll
    for (int j = 0; j < 6; j++)
      if (tid + j * 256 < 1296) hlf0[lofs[j]] = hreg[j];
    __syncthreads();
  }

  int cur = 0;
#pragma unroll 1
  for (int c4i = 0; c4i < 8; c4i++) {
    int nxt = cur ^ 1;
    float hreg[6];
    if (c4i < 7) {
      int ci0n = s2 * 32 + (c4i + 1) * 4;
#pragma unroll
      for (int j = 0; j < 6; j++) hreg[j] = pred[j] ? hup[gofs[j] + ci0n] : 0.f;
      STAGE_W(nxt, ci0n);
    }
    const float* wlc = wl[cur];
#pragma unroll 1
    for (int dtdh = 0; dtdh < 9; dtdh++) {
      int dt = dtdh / 3, dh = dtdh % 3;
#pragma unroll
      for (int cc = 0; cc < 4; cc++) {
        float hv[6];
#pragma unroll
        for (int k = 0; k < 6; k++) hv[k] = hl[cur][cc][dt][th + dh][w0 + k];
#pragma unroll
        for (int dw = 0; dw < 3; dw++) {
          float2 wf = *(const float2*)&wlc[(((dtdh * 3 + dw) * 4 + cc) << 5) + c4 * 2];
#pragma unroll
          for (int wi = 0; wi < 4; wi++) {
            float hvv = hv[wi + dw];
            acc[wi][0] += hvv * wf.x; acc[wi][1] += hvv * wf.y;
          }
        }
      }
    }
    if (c4i < 7) {
      float* hlfn = nxt ? hlf1 : hlf0;
#pragma unroll
      for (int j = 0; j < 6; j++)
        if (tid + j * 256 < 1296) hlfn[lofs[j]] = hreg[j];
    }
    __syncthreads();
    cur = nxt;
  }
#undef STAGE_W

  float* base = &pacc[(size_t)s2 * NELEM +
                      (size_t)((((b * 4 + t) * 16 + h) * 16 + w0) * 64 + coH * 32 + c4 * 2)];
#pragma unroll
  for (int wi = 0; wi < 4; wi++) {
    float2 v = make_float2(acc[wi][0], acc[wi][1]);
    *(float2*)(base + wi * 64) = v;
  }
}

// ------------------- combine partials + bias + 0.5/0.5 mix + accu + sse
// grid 512 x 4 elems/thread; wave shfl reduce + 1 atomic per block.
__global__ __launch_bounds__(256) void conv_combine_kernel(
    const float* __restrict__ pacc, const float* __restrict__ hup,
    const float* __restrict__ bq, const float* __restrict__ zcl,
    double* __restrict__ accu, double* sse, int qi)
{
  __shared__ double wsum[4];
  int tid = threadIdx.x;
  double v = 0.0;
#pragma unroll
  for (int k = 0; k < 4; k++) {
    int e = blockIdx.x * 1024 + k * 256 + tid;
    int co = e & 63;
    double cv = ((double)pacc[e] + (double)pacc[(size_t)NELEM + e]) + (double)bq[qi * 64 + co];
    double hu = (double)hup[e];
    double na = accu[e] + 0.5 * hu + 0.5 * cv;
    accu[e] = na;
    double df = na - (double)zcl[e];
    v += df * df;
  }
#pragma unroll
  for (int off = 1; off < 64; off <<= 1) v += __shfl_xor(v, off);
  if ((tid & 63) == 0) wsum[tid >> 6] = v;
  __syncthreads();
  if (tid == 0) atomicAdd(sse, ((wsum[0] + wsum[1]) + wsum[2]) + wsum[3]);
}

// ---------------------------------------------------------------- stats
__global__ __launch_bounds__(256) void bincount_kernel(const int* __restrict__ idx_cur, int* counts) {
  int i = blockIdx.x * 256 + threadIdx.x;
  if (i < NSP) atomicAdd(&counts[idx_cur[i]], 1);
}

__global__ __launch_bounds__(256) void stats_kernel(
    const int* __restrict__ counts, float* __restrict__ usage_out, double* ent, int* usedcnt)
{
  __shared__ double re[256];
  __shared__ int ru[256];
  int j = blockIdx.x * 256 + threadIdx.x;
  int cnt = counts[j];
  double p = (double)cnt / 8192.0;
  usage_out[j] = (float)p;
  re[threadIdx.x] = p * log(p + 1e-10);
  ru[threadIdx.x] = cnt > 0 ? 1 : 0;
  __syncthreads();
  for (int s = 128; s > 0; s >>= 1) {
    if (threadIdx.x < s) { re[threadIdx.x] += re[threadIdx.x + s]; ru[threadIdx.x] += ru[threadIdx.x + s]; }
    __syncthreads();
  }
  if (threadIdx.x == 0) { atomicAdd(ent, re[0]); atomicAdd(usedcnt, ru[0]); }
}

__global__ void final_kernel(const double* sse, const double* ent, const int* usedcnt, float* out) {
  if (threadIdx.x == 0) {
    out[NELEM]     = (float)(*sse * 0.25 / 524288.0 / 10.0);
    out[NELEM + 1] = (float)exp(-*ent);
    out[NELEM + 2] = (float)((double)*usedcnt / 16384.0);
  }
}

__global__ __launch_bounds__(256) void embst_kernel(const double* __restrict__ accu, float* __restrict__ out) {
  int e = blockIdx.x * 256 + threadIdx.x;
  int w = e & 15, h = (e >> 4) & 15, t = (e >> 8) & 3, c = (e >> 10) & 63, b = e >> 16;
  out[e] = (float)accu[(size_t)(((((b * 4 + t) * 16 + h) * 16 + w) * 64) + c)];
}

// ---------------------------------------------------------------- launch
extern "C" void kernel_launch(void* const* d_in, const int* in_sizes, int n_in,
                              void* d_out, int out_size, void* d_ws, size_t ws_size,
                              hipStream_t stream) {
  static const int T_PN_h[10] = {1, 1, 2, 2, 2, 4, 4, 4, 4, 4};
  static const int V_PN_h[10] = {1, 2, 3, 4, 5, 6, 8, 10, 13, 16};
  // qi from bit-exact fp64 emulation of np.linspace+argmin (ties: si=2->1, si=7->3)
  static const int QI_h[10]   = {0, 0, 1, 1, 1, 2, 2, 3, 3, 3};
  static const int NS_h[10]   = {8, 32, 144, 256, 400, 1152, 2048, 3200, 5408, 8192};
  static const int OB_h[10]   = {540675, 540683, 540715, 540859, 541115,
                                 541515, 542667, 544715, 547915, 553323};
  static const int NCH_h[10]  = {64, 64, 64, 64, 64, 32, 32, 32, 16, 16};
  static const int SPL_h[10]  = {128, 32, 8, 4, 4, 1, 1, 1, 1, 1};

  const float* z   = (const float*)d_in[0];
  const float* emb = (const float*)d_in[1];
  const float* Wq  = (const float*)d_in[2];
  const float* bq  = (const float*)d_in[3];
  float* out = (float*)d_out;
  char* ws = (char*)d_ws;

  double* accu    = (double*)(ws + WS_ACCU);
  float*  hup     = (float*)(ws + WS_HUP);
  double* rest64  = (double*)(ws + WS_REST64);
  float*  pacc    = (float*)(ws + WS_PACC);
  float4* part    = (float4*)(ws + WS_PART);
  PBest*  pbest   = (PBest*)(ws + WS_PART);
  double* ppool   = (double*)(ws + WS_PART);
  float*  zcl     = (float*)(ws + WS_ZCL);
  short*  ehf     = (short*)(ws + WS_EHF);
  short*  elf     = (short*)(ws + WS_ELF);
  float*  esq     = (float*)(ws + WS_ESQ);
  float*  twt     = (float*)(ws + WS_TWT);
  int*    idx_cur = (int*)(ws + WS_IDX);
  int*    counts  = (int*)(ws + WS_CNT);
  int*    flaglist= (int*)(ws + WS_FLAGL);
  int*    flagcnt = (int*)(ws + WS_FLAGC);
  double* sse     = (double*)(ws + WS_SSE);
  double* ent     = (double*)(ws + WS_ENT);
  int*    usedcnt = (int*)(ws + WS_USED);
  short*  rhf     = (short*)(ws + WS_RHF);
  short*  rlf     = (short*)(ws + WS_RLF);

  prep_kernel<<<10049, 256, 0, stream>>>(z, emb, Wq, accu, zcl, ehf, elf, esq, twt,
                                         counts, flagcnt, sse, ent, usedcnt);

  for (int si = 0; si < 10; si++) {
    int tpn = T_PN_h[si], pn = V_PN_h[si], N = NS_h[si];
    int NSpad = (N + 63) & ~63;
    int nch = NCH_h[si];
    int nstripes = (NCODES / nch) / 128;
    int SPL = SPL_h[si];
    if (SPL > 1) {
      dim3 pg(N, SPL);
      pool_part_kernel<<<pg, 256, 0, stream>>>(zcl, accu, ppool, N, tpn, pn, SPL);
      pool_finish_kernel<<<NSpad, 256, 0, stream>>>(ppool, rest64, rhf, rlf, N, tpn, pn, SPL);
    } else if (si == 9) {
      pool_flat_kernel<<<NELEM / 256, 256, 0, stream>>>(zcl, accu, rest64, rhf, rlf);
    } else {
      pool_kernel<<<NSpad, 256, 0, stream>>>(zcl, accu, rest64, rhf, rlf, N, tpn, pn);
    }
    dim3 ag(NSpad / 64, nch);
    argmin_kernel<<<ag, 256, 0, stream>>>(rhf, rlf, ehf, elf, esq, part, NSpad, nstripes);
    reduce_kernel<<<(N + 255) / 256, 256, 0, stream>>>(part, idx_cur, out + OB_h[si],
                                                       flagcnt + si, flaglist, N, NSpad, nch);
    dim3 rg(1024, RCH);
    refine_kernel<<<rg, 256, 0, stream>>>(rest64, emb, flagcnt + si, flaglist, pbest);
    refine_merge_kernel<<<(N + 255) / 256, 256, 0, stream>>>(pbest, flagcnt + si, flaglist,
                                                             idx_cur, out + OB_h[si]);
    upsample_kernel<<<NELEM / 256, 256, 0, stream>>>(emb, idx_cur, hup, tpn, pn);
    conv_part_kernel<<<512, 256, 0, stream>>>(hup, twt, pacc, QI_h[si]);
    conv_combine_kernel<<<512, 256, 0, stream>>>(pacc, hup, bq, zcl, accu, sse, QI_h[si]);
  }

  bincount_kernel<<<32, 256, 0, stream>>>(idx_cur, counts);
  stats_kernel<<<64, 256, 0, stream>>>(counts, out + 524291, ent, usedcnt);
  final_kernel<<<1, 64, 0, stream>>>(sse, ent, usedcnt, out);
  embst_kernel<<<NELEM / 256, 256, 0, stream>>>(accu, out);
}

// Round 12
// 1367.437 us; speedup vs baseline: 1.1997x; 1.0694x over previous
//
#include <hip/hip_runtime.h>
#include <math.h>

// MultiScaleCodebook on MI355X — round 26: conv ci-quarter occupancy + embst fusion.
// r25 = 1462us (champion). Top-5 is argmin-only (~66us, local optimum). The
// biggest unprofiled block is conv_part (fp32, <66us since r19, VALU wall
// 11.5us, but only 2 blocks/CU at grid 512 with 39KB LDS allowing 4).
// This round: (1) conv_part -> ci-QUARTER blocks (grid 1024, 16ci x 32co,
// 4 c4i iters, 4 blocks/CU): same total FMA + same staging bytes, 2x waves
// for latency hiding; pacc -> 4 exclusive f32 slots (8MB, fits); combine
// folds 4 slots in fixed order (deterministic; fp32 regroup ~1e-6, same
// class as accepted r19 change, << 0.01 refine margin). (2) conv_combine at
// si9 also writes the transposed out copy (na already in register) and the
// embst launch is deleted. All else = r25.

#define NCODES 16384
#define NELEM  524288   // 8*64*4*16*16
#define NSP    8192     // 8*4*16*16

#define RCH    8        // refine chunks
#define RCODES (NCODES / RCH)   // 2048 codes per chunk

#define WS_ACCU   0ul
#define WS_HUP    4194304ul    // hup f32, 2MB used of 4MB
#define WS_REST64 8388608ul    // rest64 f64 4MB [8388608,12582912)
#define WS_PACC   8388608ul    // pacc f32[4][NELEM] 8MB aliases rest64+part
                               // (rest64 dead after refine; part dead after reduce)
#define WS_PART   12582912ul   // <=2MB used; ppool + refine pbest alias this
#define WS_ZCL    16777216ul
#define WS_EHF    18874368ul   // emb bf16-hi frags, 2MB
#define WS_ELF    20971520ul   // emb bf16-lo frags, 2MB
#define WS_ESQ    23068672ul
#define WS_TWT    23134208ul
#define WS_IDX    24903680ul
#define WS_CNT    24936448ul
#define WS_FLAGL  25001984ul
#define WS_FLAGC  25034752ul
#define WS_SSE    25034816ul
#define WS_ENT    25034824ul
#define WS_USED   25034832ul
#define WS_RHF    25034848ul   // rest bf16-hi frags, 1MB
#define WS_RLF    26083424ul   // rest bf16-lo frags, 1MB

typedef __attribute__((ext_vector_type(8))) short short8;
typedef __attribute__((ext_vector_type(4))) float floatx4;

struct PBest { double d; int idx; int pad; };

// async 16B global->LDS: lds dest = wave-uniform base + lane*16
__device__ __forceinline__ void gl2lds16(const void* g, void* l) {
  __builtin_amdgcn_global_load_lds(
      (const __attribute__((address_space(1))) unsigned int*)g,
      (__attribute__((address_space(3))) unsigned int*)l, 16, 0, 0);
}

// round-to-nearest-even float -> bf16; also returns hi as float
__device__ inline short bf16rne(float f, float* hi) {
  unsigned u = __float_as_uint(f);
  unsigned r = (u + 0x7FFFu + ((u >> 16) & 1u)) >> 16;
  *hi = __uint_as_float(r << 16);
  return (short)r;
}

// ---------------------------------------------------------------- prep
__global__ __launch_bounds__(256) void prep_kernel(
    const float* __restrict__ z, const float* __restrict__ emb, const float* __restrict__ Wq,
    double* __restrict__ accu, float* __restrict__ zcl,
    short* __restrict__ ehf, short* __restrict__ elf,
    float* __restrict__ esq, float* __restrict__ twt,
    int* __restrict__ counts, int* __restrict__ flagcnt,
    double* sse, double* ent, int* usedcnt)
{
  int i = blockIdx.x * 256 + threadIdx.x;
  if (i < NELEM) { accu[i] = 0.0; return; }
  i -= NELEM;
  if (i < NELEM) {  // z [B,C,T,H,W] -> zcl [B,T,H,W,C]
    int c = i & 63, w = (i >> 6) & 15, h = (i >> 10) & 15, t = (i >> 14) & 3, b = i >> 16;
    zcl[i] = z[(((b * 64 + c) * 4 + t) * 16 + h) * 16 + w];
    return;
  }
  i -= NELEM;
  if (i < NCODES * 64) {  // emb -> bf16 split, MFMA B-frag order
    int j = i >> 6, c = i & 63;
    float v = emb[i];
    float hi; short h = bf16rne(v, &hi);
    float hi2; short l = bf16rne(v - hi, &hi2);
    int jt = j >> 4, nn = j & 15, hf = c >> 5, q = (c >> 3) & 3, ii = c & 7;
    size_t slot = ((size_t)(((jt * 2 + hf) * 64) + q * 16 + nn)) * 8 + ii;
    ehf[slot] = h; elf[slot] = l;
    return;
  }
  i -= NCODES * 64;
  if (i < NCODES) {  // e_sq fp32 (ranking only; refine is fp64)
    float s = 0.f;
    for (int c = 0; c < 64; c++) { float v = emb[i * 64 + c]; s += v * v; }
    esq[i] = s; return;
  }
  i -= NCODES;
  if (i < 442368) {  // twt[qi][tap][ci][co] = Wq[qi][co][ci][tap]
    int qi = i / 110592; int r = i % 110592;
    int tap = r >> 12; int ci = (r >> 6) & 63; int co = r & 63;
    twt[i] = Wq[((qi * 64 + co) * 64 + ci) * 27 + tap];
    return;
  }
  i -= 442368;
  if (i < NCODES) { counts[i] = 0; return; }
  i -= NCODES;
  if (i < 16) {
    if (i < 10) flagcnt[i] = 0;
    else if (i == 10) *sse = 0.0;
    else if (i == 11) *ent = 0.0;
    else if (i == 12) *usedcnt = 0;
  }
}

// ------------------------------------------- pool (area) + frag emit
// single-stage path (SPLIT==1 scales, si5..si8)
__global__ __launch_bounds__(256) void pool_kernel(
    const float* __restrict__ zcl, const double* __restrict__ accu,
    double* __restrict__ rest64, short* __restrict__ rhf, short* __restrict__ rlf,
    int N, int tpn, int pn)
{
  __shared__ double psum[4][64];
  int n = blockIdx.x;
  int tid = threadIdx.x;
  int c = tid & 63, ck = tid >> 6;
  if (n >= N) {  // zero pad rows so argmin frags are defined
    if (tid < 64) {
      int pt = n >> 4, m = n & 15, hf = tid >> 5, q = (tid >> 3) & 3, ii = tid & 7;
      size_t slot = ((size_t)(((pt * 2 + hf) * 64) + q * 16 + m)) * 8 + ii;
      rhf[slot] = 0; rlf[slot] = 0;
    }
    return;
  }
  int ppn = pn * pn;
  int b = n / (tpn * ppn); int r = n % (tpn * ppn);
  int u = r / ppn; r %= ppn; int v = r / pn; int x = r % pn;
  int t0 = (u * 4) / tpn, t1 = ((u + 1) * 4 + tpn - 1) / tpn;
  int h0 = (v * 16) / pn, h1 = ((v + 1) * 16 + pn - 1) / pn;
  int w0 = (x * 16) / pn, w1 = ((x + 1) * 16 + pn - 1) / pn;
  int nt = t1 - t0, nh = h1 - h0, nw = w1 - w0;
  int M = nt * nh * nw;
  int chunk = (M + 3) >> 2;
  int m0 = ck * chunk; int m1 = m0 + chunk; if (m1 > M) m1 = M;
  double s = 0.0;
  if (m0 < m1) {
    int tmp = m0 / nw; int wi = m0 - tmp * nw;
    int ti = tmp / nh; int hi = tmp - ti * nh;
    for (int m = m0; m < m1; m++) {
      size_t off = (size_t)((((b * 4 + t0 + ti) * 16 + h0 + hi) * 16 + w0 + wi) * 64 + c);
      s += (double)zcl[off] - accu[off];
      if (++wi == nw) { wi = 0; if (++hi == nh) { hi = 0; ++ti; } }
    }
  }
  psum[ck][c] = s;
  __syncthreads();
  if (tid < 64) {
    double t = ((psum[0][c] + psum[1][c]) + psum[2][c]) + psum[3][c];
    float wt = 1.f / (float)nt, wh = 1.f / (float)nh, ww = 1.f / (float)nw;
    double rv = t * (double)wt * (double)wh * (double)ww;
    rest64[(size_t)n * 64 + c] = rv;
    float rv32 = (float)rv;
    float hi; short h = bf16rne(rv32, &hi);
    float hi2; short l = bf16rne(rv32 - hi, &hi2);
    int pt = n >> 4, m = n & 15, hf = c >> 5, q = (c >> 3) & 3, ii = c & 7;
    size_t slot = ((size_t)(((pt * 2 + hf) * 64) + q * 16 + m)) * 8 + ii;
    rhf[slot] = h; rlf[slot] = l;
  }
}

// ------------------- pool flat path (si9: tpn=4, pn=16, M==1 — pure copy)
__global__ __launch_bounds__(256) void pool_flat_kernel(
    const float* __restrict__ zcl, const double* __restrict__ accu,
    double* __restrict__ rest64, short* __restrict__ rhf, short* __restrict__ rlf)
{
  int e = blockIdx.x * 256 + threadIdx.x;
  int n = e >> 6, c = e & 63;
  double rv = (double)zcl[e] - accu[e];
  rest64[e] = rv;
  float rv32 = (float)rv;
  float hi; short h = bf16rne(rv32, &hi);
  float hi2; short l = bf16rne(rv32 - hi, &hi2);
  int pt = n >> 4, m = n & 15, hf = c >> 5, q = (c >> 3) & 3, ii = c & 7;
  size_t slot = ((size_t)(((pt * 2 + hf) * 64) + q * 16 + m)) * 8 + ii;
  rhf[slot] = h; rlf[slot] = l;
}

// ------------------- pool stage 1: split-K partials (small-N scales)
__global__ __launch_bounds__(256) void pool_part_kernel(
    const float* __restrict__ zcl, const double* __restrict__ accu,
    double* __restrict__ ppool, int N, int tpn, int pn, int SPL)
{
  __shared__ double psum[4][64];
  int n = blockIdx.x;
  int sp = blockIdx.y;
  int tid = threadIdx.x;
  int c = tid & 63, ck = tid >> 6;
  int ppn = pn * pn;
  int b = n / (tpn * ppn); int r = n % (tpn * ppn);
  int u = r / ppn; r %= ppn; int v = r / pn; int x = r % pn;
  int t0 = (u * 4) / tpn, t1 = ((u + 1) * 4 + tpn - 1) / tpn;
  int h0 = (v * 16) / pn, h1 = ((v + 1) * 16 + pn - 1) / pn;
  int w0 = (x * 16) / pn, w1 = ((x + 1) * 16 + pn - 1) / pn;
  int nt = t1 - t0, nh = h1 - h0, nw = w1 - w0;
  int M = nt * nh * nw;
  int C = SPL * 4;
  int chunk = (M + C - 1) / C;
  int m0 = (sp * 4 + ck) * chunk; int m1 = m0 + chunk;
  if (m0 > M) m0 = M;
  if (m1 > M) m1 = M;
  double s = 0.0;
  if (m0 < m1) {
    int tmp = m0 / nw; int wi = m0 - tmp * nw;
    int ti = tmp / nh; int hi = tmp - ti * nh;
    for (int m = m0; m < m1; m++) {
      size_t off = (size_t)((((b * 4 + t0 + ti) * 16 + h0 + hi) * 16 + w0 + wi) * 64 + c);
      s += (double)zcl[off] - accu[off];
      if (++wi == nw) { wi = 0; if (++hi == nh) { hi = 0; ++ti; } }
    }
  }
  psum[ck][c] = s;
  __syncthreads();
  if (tid < 64) {
    double t = ((psum[0][c] + psum[1][c]) + psum[2][c]) + psum[3][c];
    ppool[((size_t)n * SPL + sp) * 64 + c] = t;
  }
}

// ------------------- pool stage 2: fold SPLIT partials + emit frags
__global__ __launch_bounds__(256) void pool_finish_kernel(
    const double* __restrict__ ppool, double* __restrict__ rest64,
    short* __restrict__ rhf, short* __restrict__ rlf,
    int N, int tpn, int pn, int SPL)
{
  __shared__ double psum[4][64];
  int n = blockIdx.x;
  int tid = threadIdx.x;
  int c = tid & 63, ck = tid >> 6;
  if (n >= N) {  // zero pad rows so argmin frags are defined
    if (tid < 64) {
      int pt = n >> 4, m = n & 15, hf = tid >> 5, q = (tid >> 3) & 3, ii = tid & 7;
      size_t slot = ((size_t)(((pt * 2 + hf) * 64) + q * 16 + m)) * 8 + ii;
      rhf[slot] = 0; rlf[slot] = 0;
    }
    return;
  }
  int ppn = pn * pn;
  int b = n / (tpn * ppn); int r = n % (tpn * ppn);
  int u = r / ppn; r %= ppn; int v = r / pn; int x = r % pn;
  int t0 = (u * 4) / tpn, t1 = ((u + 1) * 4 + tpn - 1) / tpn;
  int h0 = (v * 16) / pn, h1 = ((v + 1) * 16 + pn - 1) / pn;
  int w0 = (x * 16) / pn, w1 = ((x + 1) * 16 + pn - 1) / pn;
  int nt = t1 - t0, nh = h1 - h0, nw = w1 - w0;
  (void)b; (void)t0; (void)h0; (void)w0;
  int q4 = SPL >> 2;
  const double* pp = ppool + ((size_t)n * SPL) * 64 + c;
  double s = 0.0;
  for (int sp = ck * q4; sp < (ck + 1) * q4; sp++) s += pp[(size_t)sp * 64];
  psum[ck][c] = s;
  __syncthreads();
  if (tid < 64) {
    double t = ((psum[0][c] + psum[1][c]) + psum[2][c]) + psum[3][c];
    float wt = 1.f / (float)nt, wh = 1.f / (float)nh, ww = 1.f / (float)nw;
    double rv = t * (double)wt * (double)wh * (double)ww;
    rest64[(size_t)n * 64 + c] = rv;
    float rv32 = (float)rv;
    float hi; short h = bf16rne(rv32, &hi);
    float hi2; short l = bf16rne(rv32 - hi, &hi2);
    int pt = n >> 4, m = n & 15, hf = c >> 5, qq = (c >> 3) & 3, ii = c & 7;
    size_t slot = ((size_t)(((pt * 2 + hf) * 64) + qq * 16 + m)) * 8 + ii;
    rhf[slot] = h; rlf[slot] = l;
  }
}

// ------------------------------------------- argmin pass 1 (bf16 MFMA GEMM)
// Row-partition; A frags (hi+lo) loaded global->VGPR directly (per-lane
// coalesced 16B), no A LDS -> ~33KB LDS -> 4 blocks/CU. 6-MFMA precision.
__global__ __launch_bounds__(256) void argmin_kernel(
    const short* __restrict__ rhf, const short* __restrict__ rlf,
    const short* __restrict__ ehf, const short* __restrict__ elf,
    const float* __restrict__ esq, float4* __restrict__ part,
    int NSpad, int nstripes)
{
  __shared__ short8 Bh[8][2][64];
  __shared__ short8 Bl[8][2][64];
  __shared__ float esql[128];
  int tid = threadIdx.x;
  int pbase = blockIdx.x * 64;
  int ch = blockIdx.y;
  int wv64 = tid & ~63, ln = tid & 63;
  int w = tid >> 6, lane = tid & 63, col = lane & 15;
  const short8* sAH = (const short8*)(rhf + (size_t)pbase * 64);
  const short8* sAL = (const short8*)(rlf + (size_t)pbase * 64);
  short8 ah0 = sAH[(2 * w + 0) * 64 + lane], ah1 = sAH[(2 * w + 1) * 64 + lane];
  short8 al0 = sAL[(2 * w + 0) * 64 + lane], al1 = sAL[(2 * w + 1) * 64 + lane];
  float M1[4], M2[4]; int I1[4];
#pragma unroll
  for (int r = 0; r < 4; r++) { M1[r] = -3.4e38f; M2[r] = -3.4e38f; I1[r] = 0x7fffffff; }
  for (int s = 0; s < nstripes; s++) {
    int j0 = ch * (nstripes * 128) + s * 128;
    __syncthreads();
    {  // B frags: async linear copy
      const short8* sH = (const short8*)(ehf + (size_t)j0 * 64);
      const short8* sL = (const short8*)(elf + (size_t)j0 * 64);
      short8* dH = (short8*)Bh; short8* dL = (short8*)Bl;
#pragma unroll
      for (int it = 0; it < 4; it++) {
        int idx = it * 256 + wv64;
        gl2lds16(sH + idx + ln, dH + idx);
        gl2lds16(sL + idx + ln, dL + idx);
      }
      if (tid < 128) esql[tid] = esq[j0 + tid];
    }
    __syncthreads();
    floatx4 acc[8];
#pragma unroll
    for (int jt = 0; jt < 8; jt++) {
      float c0 = -0.5f * esql[jt * 16 + col];
      acc[jt] = (floatx4){c0, c0, c0, c0};
    }
#pragma unroll
    for (int jt = 0; jt < 8; jt++) {
      short8 bh0 = Bh[jt][0][lane], bl0 = Bl[jt][0][lane];
      short8 bh1 = Bh[jt][1][lane], bl1 = Bl[jt][1][lane];
      acc[jt] = __builtin_amdgcn_mfma_f32_16x16x32_bf16(al0, bh0, acc[jt], 0, 0, 0);
      acc[jt] = __builtin_amdgcn_mfma_f32_16x16x32_bf16(ah0, bl0, acc[jt], 0, 0, 0);
      acc[jt] = __builtin_amdgcn_mfma_f32_16x16x32_bf16(ah0, bh0, acc[jt], 0, 0, 0);
      acc[jt] = __builtin_amdgcn_mfma_f32_16x16x32_bf16(al1, bh1, acc[jt], 0, 0, 0);
      acc[jt] = __builtin_amdgcn_mfma_f32_16x16x32_bf16(ah1, bl1, acc[jt], 0, 0, 0);
      acc[jt] = __builtin_amdgcn_mfma_f32_16x16x32_bf16(ah1, bh1, acc[jt], 0, 0, 0);
    }
#pragma unroll
    for (int jt = 0; jt < 8; jt++) {
      int j = j0 + jt * 16 + col;
#pragma unroll
      for (int r = 0; r < 4; r++) {
        float a = acc[jt][r];   // a = dot - es/2 ; argmax a == argmin d
        bool c = a > M1[r];
        M2[r] = __builtin_amdgcn_fmed3f(a, M1[r], M2[r]);  // M1>=M2 invariant
        M1[r] = fmaxf(a, M1[r]);
        I1[r] = c ? j : I1[r];
      }
    }
  }
#pragma unroll
  for (int off = 1; off < 16; off <<= 1) {
#pragma unroll
    for (int r = 0; r < 4; r++) {
      float o1 = __shfl_xor(M1[r], off);
      int   oi = __shfl_xor(I1[r], off);
      float o2 = __shfl_xor(M2[r], off);
      bool bwin = (o1 > M1[r]) || (o1 == M1[r] && oi < I1[r]);
      float nm2 = bwin ? fmaxf(M1[r], o2) : fmaxf(M2[r], o1);
      if (bwin) { M1[r] = o1; I1[r] = oi; }
      M2[r] = nm2;
    }
  }
  if (col == 0) {
    int quad = lane >> 4;
#pragma unroll
    for (int r = 0; r < 4; r++) {
      int p = pbase + w * 16 + quad * 4 + r;
      part[(size_t)ch * NSpad + p] =
          make_float4(-2.f * M1[r], -2.f * M2[r], __int_as_float(I1[r]), 0.f);
    }
  }
}

// ---------------------------- merge chunks, flag near-ties to global list
__global__ __launch_bounds__(256) void reduce_kernel(
    const float4* __restrict__ part, int* __restrict__ idx_cur,
    float* __restrict__ out_idx, int* flagcnt, int* flaglist,
    int N, int NSpad, int nch)
{
  int n = blockIdx.x * 256 + threadIdx.x;
  if (n >= N) return;
  float m1 = 3.4e38f, m2 = 3.4e38f; int i1 = 0x7fffffff;
  for (int ch = 0; ch < nch; ch++) {
    float4 q = part[(size_t)ch * NSpad + n];
    float o1 = q.x, o2 = q.y; int oi = __float_as_int(q.z);
    bool bwin = (o1 < m1) || (o1 == m1 && oi < i1);
    float nm2 = bwin ? fminf(m1, o2) : fminf(m2, o1);
    if (bwin) { m1 = o1; i1 = oi; }
    m2 = nm2;
  }
  idx_cur[n] = i1;
  out_idx[n] = (float)i1;
  if (m2 - m1 < 0.01f) {
    int pos = atomicAdd(flagcnt, 1);
    flaglist[pos] = n;
  }
}

// -------------------- parallel fp64 rescan, butterfly transpose-sum (r18)
__global__ __launch_bounds__(256) void refine_kernel(
    const double* __restrict__ rest64, const float* __restrict__ emb,
    const int* __restrict__ flagcnt, const int* __restrict__ flaglist,
    PBest* __restrict__ pbest)
{
  __shared__ double bmS[4];
  __shared__ int    biS[4];
  int cnt = *flagcnt;
  int ch = blockIdx.y;
  int tid = threadIdx.x;
  int lane = tid & 63, wv = tid >> 6;
  int c4 = lane & 15;
  int g = tid >> 4;          // 16 groups of 16 lanes
  for (int f = blockIdx.x; f < cnt; f += 1024) {
    int n = flaglist[f];
    const double* rp = rest64 + (size_t)n * 64 + c4 * 4;
    double r0 = rp[0], r1 = rp[1], r2 = rp[2], r3 = rp[3];
    double best = 1e300; int bidx = 0x7fffffff;
    int jb0 = ch * RCODES + g * 128;
#pragma unroll 1
    for (int s16 = 0; s16 < 8; s16++) {
      int jb = jb0 + s16 * 16;
      double a[16];
#pragma unroll
      for (int m = 0; m < 16; m++) {
        float4 ev = *(const float4*)&emb[(size_t)(jb + m) * 64 + c4 * 4];
        double d0 = r0 - (double)ev.x, d1 = r1 - (double)ev.y;
        double d2 = r2 - (double)ev.z, d3 = r3 - (double)ev.w;
        a[m] = (d0 * d0 + d1 * d1) + (d2 * d2 + d3 * d3);
      }
#pragma unroll
      for (int p = 0; p < 4; p++) {
        int s = 1 << p;
        int bit = (lane >> p) & 1;
        int half = 8 >> p;
#pragma unroll
        for (int k = 0; k < half; k++) {
          double lo = a[2 * k], hi = a[2 * k + 1];
          double send = bit ? lo : hi;
          double keep = bit ? hi : lo;
          a[k] = keep + __shfl_xor(send, s);
        }
      }
      double tot = a[0];
      int j = jb + c4;
      if (tot < best) { best = tot; bidx = j; }  // ascending j: first min
    }
#pragma unroll
    for (int off = 1; off < 64; off <<= 1) {
      double ob = __shfl_xor(best, off);
      int    oi = __shfl_xor(bidx, off);
      if (ob < best || (ob == best && oi < bidx)) { best = ob; bidx = oi; }
    }
    if (lane == 0) { bmS[wv] = best; biS[wv] = bidx; }
    __syncthreads();
    if (tid == 0) {
      double b = bmS[0]; int bi2 = biS[0];
      for (int w2 = 1; w2 < 4; w2++) {
        double ob = bmS[w2]; int oi = biS[w2];
        if (ob < b || (ob == b && oi < bi2)) { b = ob; bi2 = oi; }
      }
      pbest[f * RCH + ch].d = b; pbest[f * RCH + ch].idx = bi2;
    }
    __syncthreads();
  }
}

// -------------------------------- fold RCH chunk results per flagged point
__global__ __launch_bounds__(256) void refine_merge_kernel(
    const PBest* __restrict__ pbest, const int* __restrict__ flagcnt,
    const int* __restrict__ flaglist, int* __restrict__ idx_cur,
    float* __restrict__ out_idx)
{
  int f = blockIdx.x * 256 + threadIdx.x;
  if (f >= *flagcnt) return;
  double best = 1e300; int bidx = 0x7fffffff;
  for (int ch = 0; ch < RCH; ch++) {
    double d = pbest[f * RCH + ch].d; int j = pbest[f * RCH + ch].idx;
    if (d < best || (d == best && j < bidx)) { best = d; bidx = j; }
  }
  int n = flaglist[f];
  idx_cur[n] = bidx;
  out_idx[n] = (float)bidx;
}

// ------------------------- trilinear upsample (f32 out)
__device__ inline void axis_map(int L, int outlen, int i, int* j0, int* j1, float* a0, float* a1) {
  if (L == 1) { *j0 = 0; *j1 = 0; *a0 = 1.f; *a1 = 0.f; return; }
  double scale = (double)L / (double)outlen;
  double src = (i + 0.5) * scale - 0.5;
  if (src < 0.0) src = 0.0;
  int i0 = (int)floor(src); if (i0 > L - 1) i0 = L - 1;
  int i1 = i0 + 1; if (i1 > L - 1) i1 = L - 1;
  double wv = src - (double)i0;
  if (i0 == i1) {
    float p = (float)(1.0 - wv), q = (float)wv;
    *a0 = p + q; *a1 = 0.f;
  } else { *a0 = (float)(1.0 - wv); *a1 = (float)wv; }
  *j0 = i0; *j1 = i1;
}

__global__ __launch_bounds__(256) void upsample_kernel(
    const float* __restrict__ emb, const int* __restrict__ idx_cur,
    float* __restrict__ hup, int tpn, int pn)
{
  int e = blockIdx.x * 256 + threadIdx.x;
  int c = e & 63, w = (e >> 6) & 15, h = (e >> 10) & 15, t = (e >> 14) & 3, b = e >> 16;
  int t0, t1, h0, h1, w0, w1; float ta0, ta1, ha0, ha1, wa0, wa1;
  axis_map(tpn, 4, t, &t0, &t1, &ta0, &ta1);
  axis_map(pn, 16, h, &h0, &h1, &ha0, &ha1);
  axis_map(pn, 16, w, &w0, &w1, &wa0, &wa1);
  int ti[2] = {t0, t1}; float ta[2] = {ta0, ta1};
  int hi[2] = {h0, h1}; float ha[2] = {ha0, ha1};
  int wi[2] = {w0, w1}; float wa[2] = {wa0, wa1};
  double val = 0.0;
  for (int a = 0; a < 2; a++)
    for (int bb = 0; bb < 2; bb++)
      for (int cc = 0; cc < 2; cc++) {
        double wgt = (double)ta[a] * (double)ha[bb] * (double)wa[cc];
        if (wgt != 0.0) {
          int code = idx_cur[((b * tpn + ti[a]) * pn + hi[bb]) * pn + wi[cc]];
          val += wgt * (double)emb[(size_t)code * 64 + c];
        }
      }
  hup[e] = (float)val;
}

// --------------------- conv3d partial — fp32, ci-QUARTER x co-half blocks
// grid 1024: bid = [b:3][t:2][hq:2][s4:2][coH:1]; block 256 = th4 x wq4 x c4(16).
// Each block: 16 ci x 32 co, 4 c4i iters, dbuf pipeline, 4 blocks/CU.
// Exclusive float2 stores into pacc[slot=s4].
#define WLV   864                 // valid float4 slots per wl buffer
#define WLPAD (WLV * 4 + 128)     // floats per buffer incl. DMA-tail pad
__global__ __launch_bounds__(256) void conv_part_kernel(
    const float* __restrict__ hup, const float* __restrict__ twt,
    float* __restrict__ pacc, int qi)
{
  __shared__ float hl[2][4][3][6][18];               // dbuf halo, 2x5184B
  __shared__ __align__(16) float wl[2][WLPAD];       // dbuf weights (padded)
  int bid = blockIdx.x;
  int coH = bid & 1, s4 = (bid >> 1) & 3, hq = (bid >> 3) & 3, t = (bid >> 5) & 3, b = bid >> 7;
  int tid = threadIdx.x;
  int c4 = tid & 15;         // co_local = c4*2 + {0,1}
  int wq = (tid >> 4) & 3;   // w0 = wq*4
  int th = tid >> 6;         // h = hq*4 + th
  int h = hq * 4 + th, w0 = wq * 4;
  int wv64 = tid & ~63, ln = tid & 63;

  int lofs[6]; int gofs[6]; bool pred[6];
#pragma unroll
  for (int j = 0; j < 6; j++) {
    int i = tid + j * 256;
    bool vs = i < 1296;
    int ii = vs ? i : 0;
    int cc = ii & 3; int jj = ii >> 2;
    int ww = jj % 18; int k = jj / 18;
    int hh = k % 6, tt = k / 6;
    int gt = t - 1 + tt, gh = hq * 4 - 1 + hh, gw = ww - 1;
    bool inb = gt >= 0 && gt < 4 && gh >= 0 && gh < 16 && gw >= 0 && gw < 16;
    lofs[j] = ((cc * 3 + tt) * 6 + hh) * 18 + ww;
    gofs[j] = inb ? ((((b * 4 + gt) * 16 + gh) * 16 + gw) * 64 + cc) : 0;
    pred[j] = vs && inb;
  }
  float* hlf0 = &hl[0][0][0][0][0];
  float* hlf1 = &hl[1][0][0][0][0];

#define STAGE_W(bb, ci0v)                                                      \
  {                                                                            \
    const float4* srcb = (const float4*)twt;                                   \
    float4* dstb = (float4*)wl[bb];                                            \
    _Pragma("unroll")                                                          \
    for (int k2 = 0; k2 < 4; k2++) {                                           \
      int idx = k2 * 256 + wv64;                                               \
      if (idx < WLV) {                                                         \
        int i2 = idx + ln; if (i2 > WLV - 1) i2 = WLV - 1;                     \
        int f4 = i2 & 7; int tc = i2 >> 3;                                     \
        int tap = tc >> 2, cc2 = tc & 3;                                       \
        const float4* g = srcb + ((size_t)((qi * 27 + tap) * 64 + (ci0v) + cc2) * 16 + coH * 8 + f4); \
        gl2lds16(g, dstb + idx);                                               \
      }                                                                        \
    }                                                                          \
  }

  float acc[4][2];
#pragma unroll
  for (int wi = 0; wi < 4; wi++) { acc[wi][0] = 0.f; acc[wi][1] = 0.f; }

  {
    int ci0 = s4 * 16;
    float hreg[6];
#pragma unroll
    for (int j = 0; j < 6; j++) hreg[j] = pred[j] ? hup[gofs[j] + ci0] : 0.f;
    STAGE_W(0, ci0);
#pragma unroll
    for (int j = 0; j < 6; j++)
      if (tid + j * 256 < 1296) hlf0[lofs[j]] = hreg[j];
    __syncthreads();
  }

  int cur = 0;
#pragma unroll 1
  for (int c4i = 0; c4i < 4; c4i++) {
    int nxt = cur ^ 1;
    float hreg[6];
    if (c4i < 3) {
      int ci0n = s4 * 16 + (c4i + 1) * 4;
#pragma unroll
      for (int j = 0; j < 6; j++) hreg[j] = pred[j] ? hup[gofs[j] + ci0n] : 0.f;
      STAGE_W(nxt, ci0n);
    }
    const float* wlc = wl[cur];
#pragma unroll 1
    for (int dtdh = 0; dtdh < 9; dtdh++) {
      int dt = dtdh / 3, dh = dtdh % 3;
#pragma unroll
      for (int cc = 0; cc < 4; cc++) {
        float hv[6];
#pragma unroll
        for (int k = 0; k < 6; k++) hv[k] = hl[cur][cc][dt][th + dh][w0 + k];
#pragma unroll
        for (int dw = 0; dw < 3; dw++) {
          float2 wf = *(const float2*)&wlc[(((dtdh * 3 + dw) * 4 + cc) << 5) + c4 * 2];
#pragma unroll
          for (int wi = 0; wi < 4; wi++) {
            float hvv = hv[wi + dw];
            acc[wi][0] += hvv * wf.x; acc[wi][1] += hvv * wf.y;
          }
        }
      }
    }
    if (c4i < 3) {
      float* hlfn = nxt ? hlf1 : hlf0;
#pragma unroll
      for (int j = 0; j < 6; j++)
        if (tid + j * 256 < 1296) hlfn[lofs[j]] = hreg[j];
    }
    __syncthreads();
    cur = nxt;
  }
#undef STAGE_W

  float* base = &pacc[(size_t)s4 * NELEM +
                      (size_t)((((b * 4 + t) * 16 + h) * 16 + w0) * 64 + coH * 32 + c4 * 2)];
#pragma unroll
  for (int wi = 0; wi < 4; wi++) {
    float2 v = make_float2(acc[wi][0], acc[wi][1]);
    *(float2*)(base + wi * 64) = v;
  }
}

// ------------------- combine 4 partials + bias + 0.5/0.5 mix + accu + sse
// grid 512 x 4 elems/thread; wave shfl reduce + 1 atomic per block.
// Last scale (emitst=1) also writes the transposed out copy (embst fusion).
__global__ __launch_bounds__(256) void conv_combine_kernel(
    const float* __restrict__ pacc, const float* __restrict__ hup,
    const float* __restrict__ bq, const float* __restrict__ zcl,
    double* __restrict__ accu, double* sse, int qi,
    float* __restrict__ out, int emitst)
{
  __shared__ double wsum[4];
  int tid = threadIdx.x;
  double v = 0.0;
#pragma unroll
  for (int k = 0; k < 4; k++) {
    int e = blockIdx.x * 1024 + k * 256 + tid;
    int co = e & 63;
    double cv = ((double)pacc[e] + (double)pacc[(size_t)NELEM + e]) +
                ((double)pacc[(size_t)2 * NELEM + e] + (double)pacc[(size_t)3 * NELEM + e]) +
                (double)bq[qi * 64 + co];
    double hu = (double)hup[e];
    double na = accu[e] + 0.5 * hu + 0.5 * cv;
    accu[e] = na;
    double df = na - (double)zcl[e];
    v += df * df;
    if (emitst) {
      int c = e & 63, w = (e >> 6) & 15, h = (e >> 10) & 15, t = (e >> 14) & 3, b = e >> 16;
      out[(size_t)(((b * 64 + c) * 4 + t) * 16 + h) * 16 + w] = (float)na;
    }
  }
#pragma unroll
  for (int off = 1; off < 64; off <<= 1) v += __shfl_xor(v, off);
  if ((tid & 63) == 0) wsum[tid >> 6] = v;
  __syncthreads();
  if (tid == 0) atomicAdd(sse, ((wsum[0] + wsum[1]) + wsum[2]) + wsum[3]);
}

// ---------------------------------------------------------------- stats
__global__ __launch_bounds__(256) void bincount_kernel(const int* __restrict__ idx_cur, int* counts) {
  int i = blockIdx.x * 256 + threadIdx.x;
  if (i < NSP) atomicAdd(&counts[idx_cur[i]], 1);
}

__global__ __launch_bounds__(256) void stats_kernel(
    const int* __restrict__ counts, float* __restrict__ usage_out, double* ent, int* usedcnt)
{
  __shared__ double re[256];
  __shared__ int ru[256];
  int j = blockIdx.x * 256 + threadIdx.x;
  int cnt = counts[j];
  double p = (double)cnt / 8192.0;
  usage_out[j] = (float)p;
  re[threadIdx.x] = p * log(p + 1e-10);
  ru[threadIdx.x] = cnt > 0 ? 1 : 0;
  __syncthreads();
  for (int s = 128; s > 0; s >>= 1) {
    if (threadIdx.x < s) { re[threadIdx.x] += re[threadIdx.x + s]; ru[threadIdx.x] += ru[threadIdx.x + s]; }
    __syncthreads();
  }
  if (threadIdx.x == 0) { atomicAdd(ent, re[0]); atomicAdd(usedcnt, ru[0]); }
}

__global__ void final_kernel(const double* sse, const double* ent, const int* usedcnt, float* out) {
  if (threadIdx.x == 0) {
    out[NELEM]     = (float)(*sse * 0.25 / 524288.0 / 10.0);
    out[NELEM + 1] = (float)exp(-*ent);
    out[NELEM + 2] = (float)((double)*usedcnt / 16384.0);
  }
}

// ---------------------------------------------------------------- launch
extern "C" void kernel_launch(void* const* d_in, const int* in_sizes, int n_in,
                              void* d_out, int out_size, void* d_ws, size_t ws_size,
                              hipStream_t stream) {
  static const int T_PN_h[10] = {1, 1, 2, 2, 2, 4, 4, 4, 4, 4};
  static const int V_PN_h[10] = {1, 2, 3, 4, 5, 6, 8, 10, 13, 16};
  // qi from bit-exact fp64 emulation of np.linspace+argmin (ties: si=2->1, si=7->3)
  static const int QI_h[10]   = {0, 0, 1, 1, 1, 2, 2, 3, 3, 3};
  static const int NS_h[10]   = {8, 32, 144, 256, 400, 1152, 2048, 3200, 5408, 8192};
  static const int OB_h[10]   = {540675, 540683, 540715, 540859, 541115,
                                 541515, 542667, 544715, 547915, 553323};
  static const int NCH_h[10]  = {64, 64, 64, 64, 64, 32, 32, 32, 16, 16};
  static const int SPL_h[10]  = {128, 32, 8, 4, 4, 1, 1, 1, 1, 1};

  const float* z   = (const float*)d_in[0];
  const float* emb = (const float*)d_in[1];
  const float* Wq  = (const float*)d_in[2];
  const float* bq  = (const float*)d_in[3];
  float* out = (float*)d_out;
  char* ws = (char*)d_ws;

  double* accu    = (double*)(ws + WS_ACCU);
  float*  hup     = (float*)(ws + WS_HUP);
  double* rest64  = (double*)(ws + WS_REST64);
  float*  pacc    = (float*)(ws + WS_PACC);
  float4* part    = (float4*)(ws + WS_PART);
  PBest*  pbest   = (PBest*)(ws + WS_PART);
  double* ppool   = (double*)(ws + WS_PART);
  float*  zcl     = (float*)(ws + WS_ZCL);
  short*  ehf     = (short*)(ws + WS_EHF);
  short*  elf     = (short*)(ws + WS_ELF);
  float*  esq     = (float*)(ws + WS_ESQ);
  float*  twt     = (float*)(ws + WS_TWT);
  int*    idx_cur = (int*)(ws + WS_IDX);
  int*    counts  = (int*)(ws + WS_CNT);
  int*    flaglist= (int*)(ws + WS_FLAGL);
  int*    flagcnt = (int*)(ws + WS_FLAGC);
  double* sse     = (double*)(ws + WS_SSE);
  double* ent     = (double*)(ws + WS_ENT);
  int*    usedcnt = (int*)(ws + WS_USED);
  short*  rhf     = (short*)(ws + WS_RHF);
  short*  rlf     = (short*)(ws + WS_RLF);

  prep_kernel<<<10049, 256, 0, stream>>>(z, emb, Wq, accu, zcl, ehf, elf, esq, twt,
                                         counts, flagcnt, sse, ent, usedcnt);

  for (int si = 0; si < 10; si++) {
    int tpn = T_PN_h[si], pn = V_PN_h[si], N = NS_h[si];
    int NSpad = (N + 63) & ~63;
    int nch = NCH_h[si];
    int nstripes = (NCODES / nch) / 128;
    int SPL = SPL_h[si];
    if (SPL > 1) {
      dim3 pg(N, SPL);
      pool_part_kernel<<<pg, 256, 0, stream>>>(zcl, accu, ppool, N, tpn, pn, SPL);
      pool_finish_kernel<<<NSpad, 256, 0, stream>>>(ppool, rest64, rhf, rlf, N, tpn, pn, SPL);
    } else if (si == 9) {
      pool_flat_kernel<<<NELEM / 256, 256, 0, stream>>>(zcl, accu, rest64, rhf, rlf);
    } else {
      pool_kernel<<<NSpad, 256, 0, stream>>>(zcl, accu, rest64, rhf, rlf, N, tpn, pn);
    }
    dim3 ag(NSpad / 64, nch);
    argmin_kernel<<<ag, 256, 0, stream>>>(rhf, rlf, ehf, elf, esq, part, NSpad, nstripes);
    reduce_kernel<<<(N + 255) / 256, 256, 0, stream>>>(part, idx_cur, out + OB_h[si],
                                                       flagcnt + si, flaglist, N, NSpad, nch);
    dim3 rg(1024, RCH);
    refine_kernel<<<rg, 256, 0, stream>>>(rest64, emb, flagcnt + si, flaglist, pbest);
    refine_merge_kernel<<<(N + 255) / 256, 256, 0, stream>>>(pbest, flagcnt + si, flaglist,
                                                             idx_cur, out + OB_h[si]);
    upsample_kernel<<<NELEM / 256, 256, 0, stream>>>(emb, idx_cur, hup, tpn, pn);
    conv_part_kernel<<<1024, 256, 0, stream>>>(hup, twt, pacc, QI_h[si]);
    conv_combine_kernel<<<512, 256, 0, stream>>>(pacc, hup, bq, zcl, accu, sse, QI_h[si],
                                                 out, si == 9 ? 1 : 0);
  }

  bincount_kernel<<<32, 256, 0, stream>>>(idx_cur, counts);
  stats_kernel<<<64, 256, 0, stream>>>(counts, out + 524291, ent, usedcnt);
  final_kernel<<<1, 64, 0, stream>>>(sse, ent, usedcnt, out);
}